// Round 7
// baseline (692.314 us; speedup 1.0000x reference)
//
#include <hip/hip_runtime.h>

#define SLOPE 0.01f
#define EPSB 1e-5f
#define INV_CNT (1.0f/131072.0f)

typedef unsigned short u16;
typedef unsigned int u32;
typedef __attribute__((ext_vector_type(8))) short s16x8;
typedef __attribute__((ext_vector_type(4))) float f4;

__device__ float g_stats[3][2][128];   // [which][sum|sq][channel]
__device__ float g_sb[3][2][128];      // [which][scale|bias][channel]
__device__ float g_part[2048][256];    // per-block partial stats [block][sum128|sq128]
__device__ int   g_cnt[3];             // completion counters
__device__ u16 g_w1h[3][128][64];      // [k][co][ci] hi
__device__ u16 g_w1l[3][128][64];      // lo
__device__ u16 g_w2h[3][128][128];
__device__ u16 g_w2l[3][128][128];
__device__ u16 g_wmh[128][128];        // [e][d]
__device__ u16 g_wml[128][128];
__device__ u16 g_wqh[128][128];        // theta
__device__ u16 g_wql[128][128];
__device__ u16 g_sT[16777216];         // 32MB: act(spa) transposed, chunked [bp][mc2][128 d][64 m]

__device__ __forceinline__ float lrelu(float x){ return x > 0.f ? x : SLOPE*x; }
__device__ __forceinline__ u16 f2b(float f){
  u32 u = __float_as_uint(f);
  return (u16)((u + 0x7fffu + ((u >> 16) & 1u)) >> 16);   // RNE
}
__device__ __forceinline__ float b2f(u16 h){ return __uint_as_float(((u32)h) << 16); }
__device__ __forceinline__ u32 pk(float a, float b){ return (u32)f2b(a) | ((u32)f2b(b) << 16); }

// ---------------- prep: zero stats/counters + fp32 weights -> bf16 hi/lo ----------------
__global__ void k_prepw(const float* __restrict__ w1, const float* __restrict__ w2,
                        const float* __restrict__ mapw, const float* __restrict__ thw){
  int idx = blockIdx.x*256 + threadIdx.x;
  if (idx < 768) ((float*)g_stats)[idx] = 0.f;
  if (idx < 3) g_cnt[idx] = 0;
  if (idx < 24576){
    int kk = idx >> 13, r = idx & 8191, co = r >> 6, ci = r & 63;
    float v = w1[co*192 + ci*3 + kk];
    u16 h = f2b(v);
    g_w1h[kk][co][ci] = h; g_w1l[kk][co][ci] = f2b(v - b2f(h));
  } else if (idx < 73728){
    int j = idx - 24576;
    int kk = j >> 14, r = j & 16383, co = r >> 7, ci = r & 127;
    float v = w2[co*384 + ci*3 + kk];
    u16 h = f2b(v);
    g_w2h[kk][co][ci] = h; g_w2l[kk][co][ci] = f2b(v - b2f(h));
  } else if (idx < 90112){
    int j = idx - 73728;
    float v = mapw[j];
    u16 h = f2b(v);
    ((u16*)g_wmh)[j] = h; ((u16*)g_wml)[j] = f2b(v - b2f(h));
  } else if (idx < 106496){
    int j = idx - 90112;
    float v = thw[j];
    u16 h = f2b(v);
    ((u16*)g_wqh)[j] = h; ((u16*)g_wql)[j] = f2b(v - b2f(h));
  }
}

// ---------------- reduce partials -> g_stats; last block finalizes scale/bias ----------------
__global__ void k_reduce(const float* __restrict__ g, const float* __restrict__ bta, int which){
  const float* base = &g_part[blockIdx.x*128][0];
  int j = threadIdx.x;
  float s = 0.f;
  #pragma unroll 4
  for (int r = 0; r < 128; ++r) s += base[r*256 + j];
  atomicAdd(&((float*)g_stats)[which*256 + j], s);
  __threadfence();
  __shared__ int lastf;
  __syncthreads();
  if (threadIdx.x == 0) lastf = (atomicAdd(&g_cnt[which], 1) == 15) ? 1 : 0;
  __syncthreads();
  if (lastf){
    __threadfence();
    if (j < 128){
      float sm = atomicAdd(&g_stats[which][0][j], 0.f);   // coherent read
      float sq = atomicAdd(&g_stats[which][1][j], 0.f);
      float mean = sm * INV_CNT;
      float var  = sq * INV_CNT - mean*mean;
      float sc = g[j] * rsqrtf(var + EPSB);
      g_sb[which][0][j] = sc;
      g_sb[which][1][j] = bta[j] - mean*sc;
    }
  }
}

// ---------------- conv1 MFMA: weights direct-from-L2, 1 barrier; y1 stored fp32 ----------------
__global__ __launch_bounds__(256, 4) void k_conv1(const float* __restrict__ x, float* __restrict__ y1f){
  __shared__ __align__(16) u16 a0h[2][34][72];
  __shared__ __align__(16) u16 a0l[2][34][72];
  const int bid = blockIdx.x;
  const int bn0 = bid*2;
  const int b = bn0 >> 8, n = bn0 & 255;
  const int tid = threadIdx.x;
  const int w = tid >> 6, l = tid & 63, quad = l >> 4, lm = l & 15;
  f4 acc[2][4];
  #pragma unroll
  for (int i = 0; i < 2; ++i)
    #pragma unroll
    for (int j = 0; j < 4; ++j) acc[i][j] = (f4)0.f;

  { // stage x -> a0h/a0l (hi/lo bf16), transposed to [t][ci]
    int nn = tid >> 7, rem = tid & 127, t = rem >> 2, ci0 = (rem & 3)*16;
    const float* px = x + ((b*32 + t)*256 + n + nn)*64 + ci0;
    u16 hh[16], ll[16];
    #pragma unroll
    for (int j = 0; j < 4; ++j){
      float4 v = *(const float4*)(px + 4*j);
      float vv[4] = {v.x, v.y, v.z, v.w};
      #pragma unroll
      for (int e = 0; e < 4; ++e){
        u16 h = f2b(vv[e]);
        hh[4*j+e] = h; ll[4*j+e] = f2b(vv[e] - b2f(h));
      }
    }
    *(uint4*)&a0h[nn][t+1][ci0]   = *(uint4*)&hh[0];
    *(uint4*)&a0h[nn][t+1][ci0+8] = *(uint4*)&hh[8];
    *(uint4*)&a0l[nn][t+1][ci0]   = *(uint4*)&ll[0];
    *(uint4*)&a0l[nn][t+1][ci0+8] = *(uint4*)&ll[8];
  }
  for (int u = tid; u < 288; u += 256){
    int a = u / 144, rr = u % 144, r = rr / 36, cw = rr % 36;
    u32* base = a ? (u32*)&a0l[r>>1][(r&1)*33][0] : (u32*)&a0h[r>>1][(r&1)*33][0];
    base[cw] = 0u;
  }
  __syncthreads();

  for (int kk = 0; kk < 3; ++kk){
    #pragma unroll
    for (int s = 0; s < 2; ++s){
      int ci0 = s*32 + quad*8;
      s16x8 wh[2], wl[2], bh[4], bl[4];
      #pragma unroll
      for (int i = 0; i < 2; ++i){
        wh[i] = *(const s16x8*)&g_w1h[kk][(2*w+i)*16 + lm][ci0];
        wl[i] = *(const s16x8*)&g_w1l[kk][(2*w+i)*16 + lm][ci0];
      }
      #pragma unroll
      for (int nt = 0; nt < 4; ++nt){
        bh[nt] = *(s16x8*)&a0h[nt>>1][(nt&1)*16 + lm + kk][ci0];
        bl[nt] = *(s16x8*)&a0l[nt>>1][(nt&1)*16 + lm + kk][ci0];
      }
      #pragma unroll
      for (int i = 0; i < 2; ++i)
        #pragma unroll
        for (int nt = 0; nt < 4; ++nt){
          acc[i][nt] = __builtin_amdgcn_mfma_f32_16x16x32_bf16(wh[i], bh[nt], acc[i][nt], 0, 0, 0);
          acc[i][nt] = __builtin_amdgcn_mfma_f32_16x16x32_bf16(wh[i], bl[nt], acc[i][nt], 0, 0, 0);
          acc[i][nt] = __builtin_amdgcn_mfma_f32_16x16x32_bf16(wl[i], bh[nt], acc[i][nt], 0, 0, 0);
        }
    }
  }
  // epilogue: D row=co(quad*4+reg), col=t(lm). Store fp32 directly.
  #pragma unroll
  for (int i = 0; i < 2; ++i){
    int co0 = (2*w+i)*16 + quad*4;
    float s0=0,s1=0,s2=0,s3=0,q0=0,q1=0,q2=0,q3=0;
    #pragma unroll
    for (int nt = 0; nt < 4; ++nt){
      f4 a = acc[i][nt];
      int nn = nt >> 1, t = (nt & 1)*16 + lm;
      *(f4*)&y1f[((bn0+nn)*32 + t)*128 + co0] = a;
      s0+=a.x; s1+=a.y; s2+=a.z; s3+=a.w;
      q0+=a.x*a.x; q1+=a.y*a.y; q2+=a.z*a.z; q3+=a.w*a.w;
    }
    #pragma unroll
    for (int m = 1; m < 16; m <<= 1){
      s0+=__shfl_xor(s0,m); s1+=__shfl_xor(s1,m); s2+=__shfl_xor(s2,m); s3+=__shfl_xor(s3,m);
      q0+=__shfl_xor(q0,m); q1+=__shfl_xor(q1,m); q2+=__shfl_xor(q2,m); q3+=__shfl_xor(q3,m);
    }
    if (lm == 0){
      f4 sv = {s0,s1,s2,s3}, qv = {q0,q1,q2,q3};
      *(f4*)&g_part[bid][co0]       = sv;
      *(f4*)&g_part[bid][128 + co0] = qv;
    }
  }
}

// ---------------- conv2 MFMA: weights direct-from-L2, 1 barrier; y1 read fp32 ----------------
__global__ __launch_bounds__(256, 4) void k_conv2(const float* __restrict__ y1f, u16* __restrict__ spa){
  __shared__ __align__(16) u16 a1s[2][34][136];
  const int bid = blockIdx.x;
  const int bn0 = bid*2;
  const int b = bn0 >> 8, n = bn0 & 255;
  const int tid = threadIdx.x;
  const int w = tid >> 6, l = tid & 63, quad = l >> 4, lm = l & 15;
  f4 acc2[4][2];
  #pragma unroll
  for (int mt = 0; mt < 4; ++mt)
    #pragma unroll
    for (int i = 0; i < 2; ++i) acc2[mt][i] = (f4)0.f;

  { // stage bn1+relu(y1 fp32) -> a1s
    int nn = tid >> 7, rem = tid & 127, t = rem >> 2, ci0 = (rem & 3)*32;
    const float* py = y1f + ((bn0+nn)*32 + t)*128;
    #pragma unroll
    for (int j = 0; j < 4; ++j){
      float4 v1 = *(const float4*)(py + ci0 + 8*j);
      float4 v2 = *(const float4*)(py + ci0 + 8*j + 4);
      float vv[8] = {v1.x, v1.y, v1.z, v1.w, v2.x, v2.y, v2.z, v2.w};
      u16 oo[8];
      #pragma unroll
      for (int e = 0; e < 8; ++e){
        int ci = ci0 + 8*j + e;
        oo[e] = f2b(fmaxf(fmaf(vv[e], g_sb[0][0][ci], g_sb[0][1][ci]), 0.f));
      }
      *(uint4*)&a1s[nn][t+1][ci0 + 8*j] = *(uint4*)&oo[0];
    }
  }
  for (int u = tid; u < 272; u += 256){
    int r = u/68, cw = u%68;
    ((u32*)&a1s[r>>1][(r&1)*33][0])[cw] = 0u;
  }
  __syncthreads();

  for (int kk = 0; kk < 3; ++kk){
    #pragma unroll
    for (int s = 0; s < 4; ++s){
      int ci0 = s*32 + quad*8;
      s16x8 ax[4], bwh[2], bwl[2];
      #pragma unroll
      for (int i = 0; i < 2; ++i){
        bwh[i] = *(const s16x8*)&g_w2h[kk][(2*w+i)*16 + lm][ci0];
        bwl[i] = *(const s16x8*)&g_w2l[kk][(2*w+i)*16 + lm][ci0];
      }
      #pragma unroll
      for (int mt = 0; mt < 4; ++mt) ax[mt] = *(s16x8*)&a1s[mt>>1][(mt&1)*16 + lm + kk][ci0];
      #pragma unroll
      for (int mt = 0; mt < 4; ++mt)
        #pragma unroll
        for (int i = 0; i < 2; ++i){
          acc2[mt][i] = __builtin_amdgcn_mfma_f32_16x16x32_bf16(ax[mt], bwh[i], acc2[mt][i], 0, 0, 0);
          acc2[mt][i] = __builtin_amdgcn_mfma_f32_16x16x32_bf16(ax[mt], bwl[i], acc2[mt][i], 0, 0, 0);
        }
    }
  }
  // epilogue: D row=t(quad*4+reg), col=co(lm); permuted spa store (pre-BN2), partial stats
  #pragma unroll
  for (int i = 0; i < 2; ++i){
    int co = (2*w+i)*16 + lm;
    float s = 0.f, q = 0.f;
    #pragma unroll
    for (int mt = 0; mt < 4; ++mt){
      f4 a = acc2[mt][i];
      int off0 = co*32 + (mt&1)*16 + quad*4;       // off = co*32 + t
      int tp = off0 >> 7, cp = off0 & 127;
      int row = (b*32 + tp)*256 + (n + (mt>>1));
      uint2 p; p.x = pk(a.x, a.y); p.y = pk(a.z, a.w);
      *(uint2*)&spa[row*128 + cp] = p;
      s += a.x + a.y + a.z + a.w;
      q += a.x*a.x + a.y*a.y + a.z*a.z + a.w*a.w;
    }
    s += __shfl_xor(s, 16); s += __shfl_xor(s, 32);
    q += __shfl_xor(q, 16); q += __shfl_xor(q, 32);
    if (l < 16){
      g_part[bid][co]       = s;
      g_part[bid][128 + co] = q;
    }
  }
}

// ---------------- gemm0 (map) MFMA: BN2+relu inline; write-back spa + g_sT; mapped hi/lo planes ----------------
__global__ __launch_bounds__(256, 4) void k_gemm0(const u16* A,
                                                  u16* spaw,
                                                  const float* __restrict__ bvec,
                                                  u16* __restrict__ mh){
  __shared__ __align__(16) u16 As[64][136];
  const u16* Wh = &g_wmh[0][0];
  const u16* Wl = &g_wml[0][0];
  const int bid = blockIdx.x;
  const int rowbase = bid * 64;
  const int tid = threadIdx.x;
  const int w = tid >> 6, l = tid & 63, quad = l >> 4, lm = l & 15;
  f4 acc[2][4];
  #pragma unroll
  for (int i = 0; i < 2; ++i)
    #pragma unroll
    for (int rt = 0; rt < 4; ++rt) acc[i][rt] = (f4)0.f;

  { int r = tid >> 2, c0 = (tid & 3)*32;
    int row = rowbase + r;
    // fused BN2+relu: channel = tp*4 + chunk, tp = (row>>8)&31, chunk = tid&3
    int c = ((row >> 8) & 31)*4 + (tid & 3);
    float sc = g_sb[1][0][c], bi = g_sb[1][1][c];
    int mrel = row & 63;
    u16* st = g_sT + (((row >> 6) * 128) << 6);   // [bp*4+mc2][128 d][64 m] chunk
    #pragma unroll
    for (int j = 0; j < 4; ++j){
      uint4 v = *(const uint4*)&A[row*128 + c0 + 8*j];
      u32 vv[4] = {v.x, v.y, v.z, v.w};
      u16 oo[8];
      #pragma unroll
      for (int e = 0; e < 4; ++e){
        oo[2*e]   = f2b(fmaxf(fmaf(b2f((u16)(vv[e] & 0xffff)), sc, bi), 0.f));
        oo[2*e+1] = f2b(fmaxf(fmaf(b2f((u16)(vv[e] >> 16)),    sc, bi), 0.f));
      }
      uint4 ov = *(uint4*)&oo[0];
      *(uint4*)&As[r][c0 + 8*j] = ov;
      *(uint4*)&spaw[row*128 + c0 + 8*j] = ov;   // activated write-back (m-major)
      #pragma unroll
      for (int e = 0; e < 8; ++e)
        st[(c0 + 8*j + e)*64 + mrel] = oo[e];    // transposed copy (d-major)
    }
  }
  __syncthreads();

  #pragma unroll
  for (int s = 0; s < 4; ++s){
    int k0 = s*32 + quad*8;
    s16x8 awh[2], awl[2], ba[4];
    #pragma unroll
    for (int i = 0; i < 2; ++i){
      awh[i] = *(const s16x8*)&Wh[((2*w+i)*16 + lm)*128 + k0];
      awl[i] = *(const s16x8*)&Wl[((2*w+i)*16 + lm)*128 + k0];
    }
    #pragma unroll
    for (int rt = 0; rt < 4; ++rt) ba[rt] = *(s16x8*)&As[rt*16 + lm][k0];
    #pragma unroll
    for (int i = 0; i < 2; ++i)
      #pragma unroll
      for (int rt = 0; rt < 4; ++rt){
        acc[i][rt] = __builtin_amdgcn_mfma_f32_16x16x32_bf16(awh[i], ba[rt], acc[i][rt], 0, 0, 0);
        acc[i][rt] = __builtin_amdgcn_mfma_f32_16x16x32_bf16(awl[i], ba[rt], acc[i][rt], 0, 0, 0);
      }
  }
  // epilogue: hi/lo planes, chunked [bp][dc][m][32]
  #pragma unroll
  for (int i = 0; i < 2; ++i){
    int e0 = (2*w+i)*16 + quad*4;
    f4 bv = *(const f4*)&bvec[e0];
    u16* ml = mh + 16777216;
    int dc = e0 >> 5, ec = e0 & 31;
    #pragma unroll
    for (int rt = 0; rt < 4; ++rt){
      int row = rowbase + rt*16 + lm;
      int bp = row >> 8, m = row & 255;
      f4 o = acc[i][rt] + bv;
      float fv[4] = {o.x, o.y, o.z, o.w};
      u16 hh[4], ll[4];
      #pragma unroll
      for (int e = 0; e < 4; ++e){
        u16 h = f2b(fv[e]);
        hh[e] = h; ll[e] = f2b(fv[e] - b2f(h));
      }
      int off = ((bp*4 + dc)*256 + m)*32 + ec;
      *(uint2*)&mh[off] = *(uint2*)&hh[0];
      *(uint2*)&ml[off] = *(uint2*)&ll[0];
    }
  }
}

// ---------------- fused adj+agg MFMA; spa pre-activated; spasT staged from g_sT (pure copy) ----------------
__global__ __launch_bounds__(256) void k_adjagg(const u16* __restrict__ mh,
                                                const u16* __restrict__ ml,
                                                const u16* __restrict__ spa,
                                                u16* __restrict__ agg){
  __shared__ __align__(16) char smem[52224];
  u16 (*mbh)[40]   = (u16(*)[40])(smem);
  u16 (*mbl)[40]   = (u16(*)[40])(smem + 20480);
  u16 (*Ps)[264]   = (u16(*)[264])(smem);            // [64][264] = 33792 B
  u16 (*spasT)[72] = (u16(*)[72])(smem + 33792);     // [128][72] = 18432 B
  // XCD-aware remap: 4 nt-blocks of one bp land consecutively on the same XCD
  const int rb = blockIdx.x;
  const int vb = (rb & 7)*256 + (rb >> 3);
  const int bp = vb >> 2;
  const int nt = vb & 3;
  const int tid = threadIdx.x;
  const int w = tid >> 6, l = tid & 63, quad = l >> 4, lm = l & 15;

  // ---- phase 1: S rows (wave w -> row-tile w) x all 256 cols, hi/lo 3-term ----
  f4 sacc[16];
  #pragma unroll
  for (int ct = 0; ct < 16; ++ct) sacc[ct] = (f4)0.f;

  for (int dc = 0; dc < 4; ++dc){
    __syncthreads();
    { // pure copy staging from pre-split chunked planes (coalesced, conflict-free)
      const u16* srch = mh + ((bp*4 + dc) << 13);
      const u16* srcl = ml + ((bp*4 + dc) << 13);
      int m0 = tid >> 2, seg = (tid & 3)*8;
      #pragma unroll
      for (int r = 0; r < 4; ++r){
        int m = m0 + r*64;
        *(uint4*)&mbh[m][seg] = *(const uint4*)&srch[m*32 + seg];
        *(uint4*)&mbl[m][seg] = *(const uint4*)&srcl[m*32 + seg];
      }
    }
    __syncthreads();
    s16x8 amh = *(s16x8*)&mbh[nt*64 + w*16 + lm][quad*8];
    s16x8 aml = *(s16x8*)&mbl[nt*64 + w*16 + lm][quad*8];
    #pragma unroll
    for (int ct = 0; ct < 16; ++ct){
      s16x8 bmh = *(s16x8*)&mbh[ct*16 + lm][quad*8];
      s16x8 bml = *(s16x8*)&mbl[ct*16 + lm][quad*8];
      sacc[ct] = __builtin_amdgcn_mfma_f32_16x16x32_bf16(amh, bmh, sacc[ct], 0, 0, 0);
      sacc[ct] = __builtin_amdgcn_mfma_f32_16x16x32_bf16(amh, bml, sacc[ct], 0, 0, 0);
      sacc[ct] = __builtin_amdgcn_mfma_f32_16x16x32_bf16(aml, bmh, sacc[ct], 0, 0, 0);
    }
  }
  __syncthreads();   // all mbuf reads done; Ps may now overlay

  // ---- softmax (regs only) -> Ps[row][m] bf16 ----
  #pragma unroll
  for (int r = 0; r < 4; ++r){
    int rowg = nt*64 + w*16 + quad*4 + r;
    float v[16]; float mx = -3.0e38f;
    #pragma unroll
    for (int ct = 0; ct < 16; ++ct){
      float t = sacc[ct][r];
      if (ct*16 + lm == rowg) t -= 1e8f;
      t = lrelu(t);
      v[ct] = t; mx = fmaxf(mx, t);
    }
    #pragma unroll
    for (int m = 1; m < 16; m <<= 1) mx = fmaxf(mx, __shfl_xor(mx, m));
    float sum = 0.f;
    #pragma unroll
    for (int ct = 0; ct < 16; ++ct){ float e = __expf(v[ct] - mx); v[ct] = e; sum += e; }
    #pragma unroll
    for (int m = 1; m < 16; m <<= 1) sum += __shfl_xor(sum, m);
    float inv = 1.0f / sum;
    #pragma unroll
    for (int ct = 0; ct < 16; ++ct)
      Ps[w*16 + quad*4 + r][ct*16 + lm] = f2b(v[ct] * inv);
  }

  // ---- phase 2: agg = P @ act (+ act for +I). spasT staged by pure copy from g_sT. ----
  f4 acc2[2][4];
  #pragma unroll
  for (int i = 0; i < 2; ++i)
    #pragma unroll
    for (int rt = 0; rt < 4; ++rt) acc2[i][rt] = (f4)0.f;

  for (int mc2 = 0; mc2 < 4; ++mc2){
    __syncthreads();
    { // copy-stage g_sT chunk [128 d][64 m] -> spasT (64B/lane contiguous)
      const u16* src = g_sT + (((bp*4 + mc2)*128) << 6) + (tid >> 1)*64 + (tid & 1)*32;
      u16* dst = &spasT[tid >> 1][(tid & 1)*32];
      *(uint4*)(dst)      = *(const uint4*)(src);
      *(uint4*)(dst + 8)  = *(const uint4*)(src + 8);
      *(uint4*)(dst + 16) = *(const uint4*)(src + 16);
      *(uint4*)(dst + 24) = *(const uint4*)(src + 24);
    }
    __syncthreads();
    #pragma unroll
    for (int ks = 0; ks < 2; ++ks){
      int m0 = ks*32 + quad*8;
      s16x8 afs[2], bfp[4];
      #pragma unroll
      for (int i = 0; i < 2; ++i) afs[i] = *(s16x8*)&spasT[(2*w+i)*16 + lm][m0];
      #pragma unroll
      for (int rt = 0; rt < 4; ++rt) bfp[rt] = *(s16x8*)&Ps[rt*16 + lm][mc2*64 + m0];
      #pragma unroll
      for (int i = 0; i < 2; ++i)
        #pragma unroll
        for (int rt = 0; rt < 4; ++rt)
          acc2[i][rt] = __builtin_amdgcn_mfma_f32_16x16x32_bf16(afs[i], bfp[rt], acc2[i][rt], 0, 0, 0);
    }
  }
  // store: D row=d(quad*4+reg), col=row(lm); +I term direct (spa pre-activated)
  #pragma unroll
  for (int i = 0; i < 2; ++i){
    int d0 = (2*w+i)*16 + quad*4;
    #pragma unroll
    for (int rt = 0; rt < 4; ++rt){
      int grow = bp*256 + nt*64 + rt*16 + lm;
      uint2 sp = *(const uint2*)&spa[grow*128 + d0];
      f4 a = acc2[i][rt];
      a.x += b2f((u16)(sp.x & 0xffff)); a.y += b2f((u16)(sp.x >> 16));
      a.z += b2f((u16)(sp.y & 0xffff)); a.w += b2f((u16)(sp.y >> 16));
      uint2 p; p.x = pk(a.x, a.y); p.y = pk(a.z, a.w);
      *(uint2*)&agg[grow*128 + d0] = p;
    }
  }
}

// ---------------- cooperative gemm1: theta GEMM + global BN-stat sync + fused BN+lrelu ----------------
// grid MUST be 1024, block 256, launch_bounds(256,4): 4 blocks/CU x 256 CU = 1024 co-resident.
__global__ __launch_bounds__(256, 4) void k_gemm1c(const u16* __restrict__ A,
                                                   const float* __restrict__ bvec,
                                                   const float* __restrict__ g,
                                                   const float* __restrict__ bta,
                                                   float* __restrict__ outp){
  __shared__ __align__(16) u16 As[64][136];       // 17408 B
  __shared__ __align__(16) u16 stash[64][132];    // 16896 B (tile0 pre-BN, bf16, 2-dword skew)
  __shared__ float sbS[2][128];                   // 1024 B   -> total 35328 <= 40960
  const u16* Wh = &g_wqh[0][0];
  const u16* Wl = &g_wql[0][0];
  const int bid = blockIdx.x;
  const int tid = threadIdx.x;
  const int w = tid >> 6, l = tid & 63, quad = l >> 4, lm = l & 15;

  f4 o0[2][4], o1[2][4];                          // pre-BN outputs (o0 also stashed in LDS)
  f4 sv[2] = {(f4)0.f, (f4)0.f}, qv[2] = {(f4)0.f, (f4)0.f};

  #pragma unroll
  for (int ti = 0; ti < 2; ++ti){
    const int rowbase = bid*128 + ti*64;
    f4 acc[2][4];
    #pragma unroll
    for (int i = 0; i < 2; ++i)
      #pragma unroll
      for (int rt = 0; rt < 4; ++rt) acc[i][rt] = (f4)0.f;

    if (ti) __syncthreads();                       // As reads of tile0 done before restage
    { int r = tid >> 2, c0 = (tid & 3)*32;
      #pragma unroll
      for (int j = 0; j < 4; ++j)
        *(uint4*)&As[r][c0 + 8*j] = *(const uint4*)&A[(rowbase + r)*128 + c0 + 8*j];
    }
    __syncthreads();

    #pragma unroll
    for (int s = 0; s < 4; ++s){
      int k0 = s*32 + quad*8;
      s16x8 awh[2], awl[2], ba[4];
      #pragma unroll
      for (int i = 0; i < 2; ++i){
        awh[i] = *(const s16x8*)&Wh[((2*w+i)*16 + lm)*128 + k0];
        awl[i] = *(const s16x8*)&Wl[((2*w+i)*16 + lm)*128 + k0];
      }
      #pragma unroll
      for (int rt = 0; rt < 4; ++rt) ba[rt] = *(s16x8*)&As[rt*16 + lm][k0];
      #pragma unroll
      for (int i = 0; i < 2; ++i)
        #pragma unroll
        for (int rt = 0; rt < 4; ++rt){
          acc[i][rt] = __builtin_amdgcn_mfma_f32_16x16x32_bf16(awh[i], ba[rt], acc[i][rt], 0, 0, 0);
          acc[i][rt] = __builtin_amdgcn_mfma_f32_16x16x32_bf16(awl[i], ba[rt], acc[i][rt], 0, 0, 0);
        }
    }
    // bias + stats; tile0 -> LDS stash (bf16), tile1 stays in regs
    #pragma unroll
    for (int i = 0; i < 2; ++i){
      int e0 = (2*w+i)*16 + quad*4;
      f4 bv = *(const f4*)&bvec[e0];
      #pragma unroll
      for (int rt = 0; rt < 4; ++rt){
        f4 o = acc[i][rt] + bv;
        if (ti == 0){
          o0[i][rt] = o;
          uint2 p; p.x = pk(o.x, o.y); p.y = pk(o.z, o.w);
          *(uint2*)&stash[rt*16 + lm][e0] = p;
        } else {
          o1[i][rt] = o;
        }
        sv[i] += o; qv[i] += o*o;
      }
    }
  }
  (void)o0;  // o0 values flow through stash (bf16) — regs freed

  // lane-reduce stats over lm, atomic into g_stats[2]
  #pragma unroll
  for (int i = 0; i < 2; ++i){
    #pragma unroll
    for (int m = 1; m < 16; m <<= 1){
      sv[i].x+=__shfl_xor(sv[i].x,m); sv[i].y+=__shfl_xor(sv[i].y,m);
      sv[i].z+=__shfl_xor(sv[i].z,m); sv[i].w+=__shfl_xor(sv[i].w,m);
      qv[i].x+=__shfl_xor(qv[i].x,m); qv[i].y+=__shfl_xor(qv[i].y,m);
      qv[i].z+=__shfl_xor(qv[i].z,m); qv[i].w+=__shfl_xor(qv[i].w,m);
    }
    if (lm == 0){
      int e0 = (2*w+i)*16 + quad*4;
      atomicAdd(&g_stats[2][0][e0+0], sv[i].x); atomicAdd(&g_stats[2][0][e0+1], sv[i].y);
      atomicAdd(&g_stats[2][0][e0+2], sv[i].z); atomicAdd(&g_stats[2][0][e0+3], sv[i].w);
      atomicAdd(&g_stats[2][1][e0+0], qv[i].x); atomicAdd(&g_stats[2][1][e0+1], qv[i].y);
      atomicAdd(&g_stats[2][1][e0+2], qv[i].z); atomicAdd(&g_stats[2][1][e0+3], qv[i].w);
    }
  }
  __threadfence();
  __syncthreads();
  if (tid == 0){
    atomicAdd(&g_cnt[2], 1);
    while (atomicAdd(&g_cnt[2], 0) < 1024) __builtin_amdgcn_s_sleep(16);
  }
  __syncthreads();
  __threadfence();
  // finalize scale/bias (coherent atomic reads)
  if (tid < 128){
    float sm = atomicAdd(&g_stats[2][0][tid], 0.f);
    float sq = atomicAdd(&g_stats[2][1][tid], 0.f);
    float mean = sm * INV_CNT;
    float var  = sq * INV_CNT - mean*mean;
    float sc = g[tid] * rsqrtf(var + EPSB);
    sbS[0][tid] = sc;
    sbS[1][tid] = bta[tid] - mean*sc;
  }
  __syncthreads();
  // apply BN + lrelu, write final fp32
  #pragma unroll
  for (int i = 0; i < 2; ++i){
    int e0 = (2*w+i)*16 + quad*4;
    f4 sc = *(const f4*)&sbS[0][e0];
    f4 bi = *(const f4*)&sbS[1][e0];
    #pragma unroll
    for (int rt = 0; rt < 4; ++rt){
      // tile0 from stash (bf16-rounded pre-BN)
      uint2 p = *(const uint2*)&stash[rt*16 + lm][e0];
      f4 t0;
      t0.x = b2f((u16)(p.x & 0xffff)); t0.y = b2f((u16)(p.x >> 16));
      t0.z = b2f((u16)(p.y & 0xffff)); t0.w = b2f((u16)(p.y >> 16));
      f4 r0;
      r0.x = lrelu(fmaf(t0.x, sc.x, bi.x)); r0.y = lrelu(fmaf(t0.y, sc.y, bi.y));
      r0.z = lrelu(fmaf(t0.z, sc.z, bi.z)); r0.w = lrelu(fmaf(t0.w, sc.w, bi.w));
      *(f4*)&outp[(bid*128 + rt*16 + lm)*128 + e0] = r0;
      // tile1 from regs (exact fp32 pre-BN)
      f4 o = o1[i][rt];
      f4 r1;
      r1.x = lrelu(fmaf(o.x, sc.x, bi.x)); r1.y = lrelu(fmaf(o.y, sc.y, bi.y));
      r1.z = lrelu(fmaf(o.z, sc.z, bi.z)); r1.w = lrelu(fmaf(o.w, sc.w, bi.w));
      *(f4*)&outp[(bid*128 + 64 + rt*16 + lm)*128 + e0] = r1;
    }
  }
}

extern "C" void kernel_launch(void* const* d_in, const int* in_sizes, int n_in,
                              void* d_out, int out_size, void* d_ws, size_t ws_size,
                              hipStream_t stream) {
  const float* x    = (const float*)d_in[0];
  const float* w1   = (const float*)d_in[1];
  const float* bn1g = (const float*)d_in[2];
  const float* bn1b = (const float*)d_in[3];
  const float* w2   = (const float*)d_in[4];
  const float* bn2g = (const float*)d_in[5];
  const float* bn2b = (const float*)d_in[6];
  const float* mapw = (const float*)d_in[7];
  const float* mapb = (const float*)d_in[8];
  const float* thw  = (const float*)d_in[9];
  const float* thb  = (const float*)d_in[10];
  const float* bnSg = (const float*)d_in[11];
  const float* bnSb = (const float*)d_in[12];
  float* outp = (float*)d_out;

  // ws (64 MB): spa (16M bf16; pre-BN2 until gemm0 activates in place) + agg (16M bf16)
  u16* spa = (u16*)d_ws;
  u16* agg = spa + 16777216;

  // d_out scratch phases: y1 fp32 (64 MB) -> mapped hi/lo planes (mh 32MB + ml 32MB) -> out fp32
  float* y1f = (float*)d_out;
  u16* mh    = (u16*)d_out;

  k_prepw<<<416, 256, 0, stream>>>(w1, w2, mapw, thw);
  k_conv1<<<2048, 256, 0, stream>>>(x, y1f);
  k_reduce<<<16, 256, 0, stream>>>(bn1g, bn1b, 0);
  k_conv2<<<2048, 256, 0, stream>>>(y1f, spa);
  k_reduce<<<16, 256, 0, stream>>>(bn2g, bn2b, 1);
  k_gemm0<<<2048, 256, 0, stream>>>(spa, spa, mapb, mh);
  k_adjagg<<<2048, 256, 0, stream>>>(mh, mh + 16777216, spa, agg);
  k_gemm1c<<<1024, 256, 0, stream>>>(agg, thb, bnSg, bnSb, outp);
}

// Round 8
// 658.374 us; speedup vs baseline: 1.0516x; 1.0516x over previous
//
#include <hip/hip_runtime.h>

#define SLOPE 0.01f
#define EPSB 1e-5f
#define INV_CNT (1.0f/131072.0f)

typedef unsigned short u16;
typedef unsigned int u32;
typedef __attribute__((ext_vector_type(8))) short s16x8;
typedef __attribute__((ext_vector_type(4))) float f4;

__device__ float g_stats[3][2][128];   // [which][sum|sq][channel]
__device__ float g_sb[3][2][128];      // [which][scale|bias][channel]
__device__ float g_part[2048][256];    // per-block partial stats [block][sum128|sq128]
__device__ int   g_cnt[3];             // completion counters
__device__ u16 g_w1h[3][128][64];      // [k][co][ci] hi
__device__ u16 g_w1l[3][128][64];      // lo
__device__ u16 g_w2h[3][128][128];
__device__ u16 g_w2l[3][128][128];
__device__ u16 g_wmh[128][128];        // [e][d]
__device__ u16 g_wml[128][128];
__device__ u16 g_wqh[128][128];        // theta
__device__ u16 g_wql[128][128];
__device__ u16 g_sT[16777216];         // 32MB: act(spa) transposed, chunked [bp][mc2][128 d][64 m]

__device__ __forceinline__ float lrelu(float x){ return x > 0.f ? x : SLOPE*x; }
__device__ __forceinline__ u16 f2b(float f){
  u32 u = __float_as_uint(f);
  return (u16)((u + 0x7fffu + ((u >> 16) & 1u)) >> 16);   // RNE
}
__device__ __forceinline__ float b2f(u16 h){ return __uint_as_float(((u32)h) << 16); }
__device__ __forceinline__ u32 pk(float a, float b){ return (u32)f2b(a) | ((u32)f2b(b) << 16); }

// ---------------- prep: zero stats/counters + fp32 weights -> bf16 hi/lo ----------------
__global__ void k_prepw(const float* __restrict__ w1, const float* __restrict__ w2,
                        const float* __restrict__ mapw, const float* __restrict__ thw){
  int idx = blockIdx.x*256 + threadIdx.x;
  if (idx < 768) ((float*)g_stats)[idx] = 0.f;
  if (idx < 3) g_cnt[idx] = 0;
  if (idx < 24576){
    int kk = idx >> 13, r = idx & 8191, co = r >> 6, ci = r & 63;
    float v = w1[co*192 + ci*3 + kk];
    u16 h = f2b(v);
    g_w1h[kk][co][ci] = h; g_w1l[kk][co][ci] = f2b(v - b2f(h));
  } else if (idx < 73728){
    int j = idx - 24576;
    int kk = j >> 14, r = j & 16383, co = r >> 7, ci = r & 127;
    float v = w2[co*384 + ci*3 + kk];
    u16 h = f2b(v);
    g_w2h[kk][co][ci] = h; g_w2l[kk][co][ci] = f2b(v - b2f(h));
  } else if (idx < 90112){
    int j = idx - 73728;
    float v = mapw[j];
    u16 h = f2b(v);
    ((u16*)g_wmh)[j] = h; ((u16*)g_wml)[j] = f2b(v - b2f(h));
  } else if (idx < 106496){
    int j = idx - 90112;
    float v = thw[j];
    u16 h = f2b(v);
    ((u16*)g_wqh)[j] = h; ((u16*)g_wql)[j] = f2b(v - b2f(h));
  }
}

// ---------------- reduce partials -> g_stats; last block finalizes scale/bias ----------------
__global__ void k_reduce(const float* __restrict__ g, const float* __restrict__ bta, int which){
  const float* base = &g_part[blockIdx.x*128][0];
  int j = threadIdx.x;
  float s = 0.f;
  #pragma unroll 4
  for (int r = 0; r < 128; ++r) s += base[r*256 + j];
  atomicAdd(&((float*)g_stats)[which*256 + j], s);
  __threadfence();
  __shared__ int lastf;
  __syncthreads();
  if (threadIdx.x == 0) lastf = (atomicAdd(&g_cnt[which], 1) == 15) ? 1 : 0;
  __syncthreads();
  if (lastf){
    __threadfence();
    if (j < 128){
      float sm = atomicAdd(&g_stats[which][0][j], 0.f);   // coherent read
      float sq = atomicAdd(&g_stats[which][1][j], 0.f);
      float mean = sm * INV_CNT;
      float var  = sq * INV_CNT - mean*mean;
      float sc = g[j] * rsqrtf(var + EPSB);
      g_sb[which][0][j] = sc;
      g_sb[which][1][j] = bta[j] - mean*sc;
    }
  }
}

// ---------------- conv1 MFMA: weights direct-from-L2, 1 barrier; y1 stored fp32 ----------------
__global__ __launch_bounds__(256, 4) void k_conv1(const float* __restrict__ x, float* __restrict__ y1f){
  __shared__ __align__(16) u16 a0h[2][34][72];
  __shared__ __align__(16) u16 a0l[2][34][72];
  const int bid = blockIdx.x;
  const int bn0 = bid*2;
  const int b = bn0 >> 8, n = bn0 & 255;
  const int tid = threadIdx.x;
  const int w = tid >> 6, l = tid & 63, quad = l >> 4, lm = l & 15;
  f4 acc[2][4];
  #pragma unroll
  for (int i = 0; i < 2; ++i)
    #pragma unroll
    for (int j = 0; j < 4; ++j) acc[i][j] = (f4)0.f;

  { // stage x -> a0h/a0l (hi/lo bf16), transposed to [t][ci]
    int nn = tid >> 7, rem = tid & 127, t = rem >> 2, ci0 = (rem & 3)*16;
    const float* px = x + ((b*32 + t)*256 + n + nn)*64 + ci0;
    u16 hh[16], ll[16];
    #pragma unroll
    for (int j = 0; j < 4; ++j){
      float4 v = *(const float4*)(px + 4*j);
      float vv[4] = {v.x, v.y, v.z, v.w};
      #pragma unroll
      for (int e = 0; e < 4; ++e){
        u16 h = f2b(vv[e]);
        hh[4*j+e] = h; ll[4*j+e] = f2b(vv[e] - b2f(h));
      }
    }
    *(uint4*)&a0h[nn][t+1][ci0]   = *(uint4*)&hh[0];
    *(uint4*)&a0h[nn][t+1][ci0+8] = *(uint4*)&hh[8];
    *(uint4*)&a0l[nn][t+1][ci0]   = *(uint4*)&ll[0];
    *(uint4*)&a0l[nn][t+1][ci0+8] = *(uint4*)&ll[8];
  }
  for (int u = tid; u < 288; u += 256){
    int a = u / 144, rr = u % 144, r = rr / 36, cw = rr % 36;
    u32* base = a ? (u32*)&a0l[r>>1][(r&1)*33][0] : (u32*)&a0h[r>>1][(r&1)*33][0];
    base[cw] = 0u;
  }
  __syncthreads();

  for (int kk = 0; kk < 3; ++kk){
    #pragma unroll
    for (int s = 0; s < 2; ++s){
      int ci0 = s*32 + quad*8;
      s16x8 wh[2], wl[2], bh[4], bl[4];
      #pragma unroll
      for (int i = 0; i < 2; ++i){
        wh[i] = *(const s16x8*)&g_w1h[kk][(2*w+i)*16 + lm][ci0];
        wl[i] = *(const s16x8*)&g_w1l[kk][(2*w+i)*16 + lm][ci0];
      }
      #pragma unroll
      for (int nt = 0; nt < 4; ++nt){
        bh[nt] = *(s16x8*)&a0h[nt>>1][(nt&1)*16 + lm + kk][ci0];
        bl[nt] = *(s16x8*)&a0l[nt>>1][(nt&1)*16 + lm + kk][ci0];
      }
      #pragma unroll
      for (int i = 0; i < 2; ++i)
        #pragma unroll
        for (int nt = 0; nt < 4; ++nt){
          acc[i][nt] = __builtin_amdgcn_mfma_f32_16x16x32_bf16(wh[i], bh[nt], acc[i][nt], 0, 0, 0);
          acc[i][nt] = __builtin_amdgcn_mfma_f32_16x16x32_bf16(wh[i], bl[nt], acc[i][nt], 0, 0, 0);
          acc[i][nt] = __builtin_amdgcn_mfma_f32_16x16x32_bf16(wl[i], bh[nt], acc[i][nt], 0, 0, 0);
        }
    }
  }
  // epilogue: D row=co(quad*4+reg), col=t(lm). Store fp32 directly.
  #pragma unroll
  for (int i = 0; i < 2; ++i){
    int co0 = (2*w+i)*16 + quad*4;
    float s0=0,s1=0,s2=0,s3=0,q0=0,q1=0,q2=0,q3=0;
    #pragma unroll
    for (int nt = 0; nt < 4; ++nt){
      f4 a = acc[i][nt];
      int nn = nt >> 1, t = (nt & 1)*16 + lm;
      *(f4*)&y1f[((bn0+nn)*32 + t)*128 + co0] = a;
      s0+=a.x; s1+=a.y; s2+=a.z; s3+=a.w;
      q0+=a.x*a.x; q1+=a.y*a.y; q2+=a.z*a.z; q3+=a.w*a.w;
    }
    #pragma unroll
    for (int m = 1; m < 16; m <<= 1){
      s0+=__shfl_xor(s0,m); s1+=__shfl_xor(s1,m); s2+=__shfl_xor(s2,m); s3+=__shfl_xor(s3,m);
      q0+=__shfl_xor(q0,m); q1+=__shfl_xor(q1,m); q2+=__shfl_xor(q2,m); q3+=__shfl_xor(q3,m);
    }
    if (lm == 0){
      f4 sv = {s0,s1,s2,s3}, qv = {q0,q1,q2,q3};
      *(f4*)&g_part[bid][co0]       = sv;
      *(f4*)&g_part[bid][128 + co0] = qv;
    }
  }
}

// ---------------- conv2 MFMA: weights direct-from-L2, 1 barrier; y1 read fp32 ----------------
__global__ __launch_bounds__(256, 4) void k_conv2(const float* __restrict__ y1f, u16* __restrict__ spa){
  __shared__ __align__(16) u16 a1s[2][34][136];
  const int bid = blockIdx.x;
  const int bn0 = bid*2;
  const int b = bn0 >> 8, n = bn0 & 255;
  const int tid = threadIdx.x;
  const int w = tid >> 6, l = tid & 63, quad = l >> 4, lm = l & 15;
  f4 acc2[4][2];
  #pragma unroll
  for (int mt = 0; mt < 4; ++mt)
    #pragma unroll
    for (int i = 0; i < 2; ++i) acc2[mt][i] = (f4)0.f;

  { // stage bn1+relu(y1 fp32) -> a1s
    int nn = tid >> 7, rem = tid & 127, t = rem >> 2, ci0 = (rem & 3)*32;
    const float* py = y1f + ((bn0+nn)*32 + t)*128;
    #pragma unroll
    for (int j = 0; j < 4; ++j){
      float4 v1 = *(const float4*)(py + ci0 + 8*j);
      float4 v2 = *(const float4*)(py + ci0 + 8*j + 4);
      float vv[8] = {v1.x, v1.y, v1.z, v1.w, v2.x, v2.y, v2.z, v2.w};
      u16 oo[8];
      #pragma unroll
      for (int e = 0; e < 8; ++e){
        int ci = ci0 + 8*j + e;
        oo[e] = f2b(fmaxf(fmaf(vv[e], g_sb[0][0][ci], g_sb[0][1][ci]), 0.f));
      }
      *(uint4*)&a1s[nn][t+1][ci0 + 8*j] = *(uint4*)&oo[0];
    }
  }
  for (int u = tid; u < 272; u += 256){
    int r = u/68, cw = u%68;
    ((u32*)&a1s[r>>1][(r&1)*33][0])[cw] = 0u;
  }
  __syncthreads();

  for (int kk = 0; kk < 3; ++kk){
    #pragma unroll
    for (int s = 0; s < 4; ++s){
      int ci0 = s*32 + quad*8;
      s16x8 ax[4], bwh[2], bwl[2];
      #pragma unroll
      for (int i = 0; i < 2; ++i){
        bwh[i] = *(const s16x8*)&g_w2h[kk][(2*w+i)*16 + lm][ci0];
        bwl[i] = *(const s16x8*)&g_w2l[kk][(2*w+i)*16 + lm][ci0];
      }
      #pragma unroll
      for (int mt = 0; mt < 4; ++mt) ax[mt] = *(s16x8*)&a1s[mt>>1][(mt&1)*16 + lm + kk][ci0];
      #pragma unroll
      for (int mt = 0; mt < 4; ++mt)
        #pragma unroll
        for (int i = 0; i < 2; ++i){
          acc2[mt][i] = __builtin_amdgcn_mfma_f32_16x16x32_bf16(ax[mt], bwh[i], acc2[mt][i], 0, 0, 0);
          acc2[mt][i] = __builtin_amdgcn_mfma_f32_16x16x32_bf16(ax[mt], bwl[i], acc2[mt][i], 0, 0, 0);
        }
    }
  }
  // epilogue: D row=t(quad*4+reg), col=co(lm); permuted spa store (pre-BN2), partial stats
  #pragma unroll
  for (int i = 0; i < 2; ++i){
    int co = (2*w+i)*16 + lm;
    float s = 0.f, q = 0.f;
    #pragma unroll
    for (int mt = 0; mt < 4; ++mt){
      f4 a = acc2[mt][i];
      int off0 = co*32 + (mt&1)*16 + quad*4;       // off = co*32 + t
      int tp = off0 >> 7, cp = off0 & 127;
      int row = (b*32 + tp)*256 + (n + (mt>>1));
      uint2 p; p.x = pk(a.x, a.y); p.y = pk(a.z, a.w);
      *(uint2*)&spa[row*128 + cp] = p;
      s += a.x + a.y + a.z + a.w;
      q += a.x*a.x + a.y*a.y + a.z*a.z + a.w*a.w;
    }
    s += __shfl_xor(s, 16); s += __shfl_xor(s, 32);
    q += __shfl_xor(q, 16); q += __shfl_xor(q, 32);
    if (l < 16){
      g_part[bid][co]       = s;
      g_part[bid][128 + co] = q;
    }
  }
}

// ---------------- gemm0 (map) MFMA: BN2+relu inline; write-back spa + g_sT; mapped hi/lo planes ----------------
__global__ __launch_bounds__(256, 4) void k_gemm0(const u16* A,
                                                  u16* spaw,
                                                  const float* __restrict__ bvec,
                                                  u16* __restrict__ mh){
  __shared__ __align__(16) u16 As[64][136];
  const u16* Wh = &g_wmh[0][0];
  const u16* Wl = &g_wml[0][0];
  const int bid = blockIdx.x;
  const int rowbase = bid * 64;
  const int tid = threadIdx.x;
  const int w = tid >> 6, l = tid & 63, quad = l >> 4, lm = l & 15;
  f4 acc[2][4];
  #pragma unroll
  for (int i = 0; i < 2; ++i)
    #pragma unroll
    for (int rt = 0; rt < 4; ++rt) acc[i][rt] = (f4)0.f;

  { int r = tid >> 2, c0 = (tid & 3)*32;
    int row = rowbase + r;
    // fused BN2+relu: channel = tp*4 + chunk, tp = (row>>8)&31, chunk = tid&3
    int c = ((row >> 8) & 31)*4 + (tid & 3);
    float sc = g_sb[1][0][c], bi = g_sb[1][1][c];
    int mrel = row & 63;
    u16* st = g_sT + (((row >> 6) * 128) << 6);   // [bp*4+mc2][128 d][64 m] chunk
    #pragma unroll
    for (int j = 0; j < 4; ++j){
      uint4 v = *(const uint4*)&A[row*128 + c0 + 8*j];
      u32 vv[4] = {v.x, v.y, v.z, v.w};
      u16 oo[8];
      #pragma unroll
      for (int e = 0; e < 4; ++e){
        oo[2*e]   = f2b(fmaxf(fmaf(b2f((u16)(vv[e] & 0xffff)), sc, bi), 0.f));
        oo[2*e+1] = f2b(fmaxf(fmaf(b2f((u16)(vv[e] >> 16)),    sc, bi), 0.f));
      }
      uint4 ov = *(uint4*)&oo[0];
      *(uint4*)&As[r][c0 + 8*j] = ov;
      *(uint4*)&spaw[row*128 + c0 + 8*j] = ov;   // activated write-back (m-major)
      #pragma unroll
      for (int e = 0; e < 8; ++e)
        st[(c0 + 8*j + e)*64 + mrel] = oo[e];    // transposed copy (d-major)
    }
  }
  __syncthreads();

  #pragma unroll
  for (int s = 0; s < 4; ++s){
    int k0 = s*32 + quad*8;
    s16x8 awh[2], awl[2], ba[4];
    #pragma unroll
    for (int i = 0; i < 2; ++i){
      awh[i] = *(const s16x8*)&Wh[((2*w+i)*16 + lm)*128 + k0];
      awl[i] = *(const s16x8*)&Wl[((2*w+i)*16 + lm)*128 + k0];
    }
    #pragma unroll
    for (int rt = 0; rt < 4; ++rt) ba[rt] = *(s16x8*)&As[rt*16 + lm][k0];
    #pragma unroll
    for (int i = 0; i < 2; ++i)
      #pragma unroll
      for (int rt = 0; rt < 4; ++rt){
        acc[i][rt] = __builtin_amdgcn_mfma_f32_16x16x32_bf16(awh[i], ba[rt], acc[i][rt], 0, 0, 0);
        acc[i][rt] = __builtin_amdgcn_mfma_f32_16x16x32_bf16(awl[i], ba[rt], acc[i][rt], 0, 0, 0);
      }
  }
  // epilogue: hi/lo planes, chunked [bp][dc][m][32]
  #pragma unroll
  for (int i = 0; i < 2; ++i){
    int e0 = (2*w+i)*16 + quad*4;
    f4 bv = *(const f4*)&bvec[e0];
    u16* ml = mh + 16777216;
    int dc = e0 >> 5, ec = e0 & 31;
    #pragma unroll
    for (int rt = 0; rt < 4; ++rt){
      int row = rowbase + rt*16 + lm;
      int bp = row >> 8, m = row & 255;
      f4 o = acc[i][rt] + bv;
      float fv[4] = {o.x, o.y, o.z, o.w};
      u16 hh[4], ll[4];
      #pragma unroll
      for (int e = 0; e < 4; ++e){
        u16 h = f2b(fv[e]);
        hh[e] = h; ll[e] = f2b(fv[e] - b2f(h));
      }
      int off = ((bp*4 + dc)*256 + m)*32 + ec;
      *(uint2*)&mh[off] = *(uint2*)&hh[0];
      *(uint2*)&ml[off] = *(uint2*)&ll[0];
    }
  }
}

// ---------------- fused adj+agg MFMA; spa pre-activated; spasT staged from g_sT (pure copy) ----------------
__global__ __launch_bounds__(256) void k_adjagg(const u16* __restrict__ mh,
                                                const u16* __restrict__ ml,
                                                const u16* __restrict__ spa,
                                                u16* __restrict__ agg){
  __shared__ __align__(16) char smem[52224];
  u16 (*mbh)[40]   = (u16(*)[40])(smem);
  u16 (*mbl)[40]   = (u16(*)[40])(smem + 20480);
  u16 (*Ps)[264]   = (u16(*)[264])(smem);            // [64][264] = 33792 B
  u16 (*spasT)[72] = (u16(*)[72])(smem + 33792);     // [128][72] = 18432 B
  // XCD-aware remap: 4 nt-blocks of one bp land consecutively on the same XCD
  const int rb = blockIdx.x;
  const int vb = (rb & 7)*256 + (rb >> 3);
  const int bp = vb >> 2;
  const int nt = vb & 3;
  const int tid = threadIdx.x;
  const int w = tid >> 6, l = tid & 63, quad = l >> 4, lm = l & 15;

  // ---- phase 1: S rows (wave w -> row-tile w) x all 256 cols, hi/lo 3-term ----
  f4 sacc[16];
  #pragma unroll
  for (int ct = 0; ct < 16; ++ct) sacc[ct] = (f4)0.f;

  for (int dc = 0; dc < 4; ++dc){
    __syncthreads();
    { // pure copy staging from pre-split chunked planes (coalesced, conflict-free)
      const u16* srch = mh + ((bp*4 + dc) << 13);
      const u16* srcl = ml + ((bp*4 + dc) << 13);
      int m0 = tid >> 2, seg = (tid & 3)*8;
      #pragma unroll
      for (int r = 0; r < 4; ++r){
        int m = m0 + r*64;
        *(uint4*)&mbh[m][seg] = *(const uint4*)&srch[m*32 + seg];
        *(uint4*)&mbl[m][seg] = *(const uint4*)&srcl[m*32 + seg];
      }
    }
    __syncthreads();
    s16x8 amh = *(s16x8*)&mbh[nt*64 + w*16 + lm][quad*8];
    s16x8 aml = *(s16x8*)&mbl[nt*64 + w*16 + lm][quad*8];
    #pragma unroll
    for (int ct = 0; ct < 16; ++ct){
      s16x8 bmh = *(s16x8*)&mbh[ct*16 + lm][quad*8];
      s16x8 bml = *(s16x8*)&mbl[ct*16 + lm][quad*8];
      sacc[ct] = __builtin_amdgcn_mfma_f32_16x16x32_bf16(amh, bmh, sacc[ct], 0, 0, 0);
      sacc[ct] = __builtin_amdgcn_mfma_f32_16x16x32_bf16(amh, bml, sacc[ct], 0, 0, 0);
      sacc[ct] = __builtin_amdgcn_mfma_f32_16x16x32_bf16(aml, bmh, sacc[ct], 0, 0, 0);
    }
  }
  __syncthreads();   // all mbuf reads done; Ps may now overlay

  // ---- softmax (regs only) -> Ps[row][m] bf16 ----
  #pragma unroll
  for (int r = 0; r < 4; ++r){
    int rowg = nt*64 + w*16 + quad*4 + r;
    float v[16]; float mx = -3.0e38f;
    #pragma unroll
    for (int ct = 0; ct < 16; ++ct){
      float t = sacc[ct][r];
      if (ct*16 + lm == rowg) t -= 1e8f;
      t = lrelu(t);
      v[ct] = t; mx = fmaxf(mx, t);
    }
    #pragma unroll
    for (int m = 1; m < 16; m <<= 1) mx = fmaxf(mx, __shfl_xor(mx, m));
    float sum = 0.f;
    #pragma unroll
    for (int ct = 0; ct < 16; ++ct){ float e = __expf(v[ct] - mx); v[ct] = e; sum += e; }
    #pragma unroll
    for (int m = 1; m < 16; m <<= 1) sum += __shfl_xor(sum, m);
    float inv = 1.0f / sum;
    #pragma unroll
    for (int ct = 0; ct < 16; ++ct)
      Ps[w*16 + quad*4 + r][ct*16 + lm] = f2b(v[ct] * inv);
  }

  // ---- phase 2: agg = P @ act (+ act for +I). spasT staged by pure copy from g_sT. ----
  f4 acc2[2][4];
  #pragma unroll
  for (int i = 0; i < 2; ++i)
    #pragma unroll
    for (int rt = 0; rt < 4; ++rt) acc2[i][rt] = (f4)0.f;

  for (int mc2 = 0; mc2 < 4; ++mc2){
    __syncthreads();
    { // copy-stage g_sT chunk [128 d][64 m] -> spasT (64B/lane contiguous)
      const u16* src = g_sT + (((bp*4 + mc2)*128) << 6) + (tid >> 1)*64 + (tid & 1)*32;
      u16* dst = &spasT[tid >> 1][(tid & 1)*32];
      *(uint4*)(dst)      = *(const uint4*)(src);
      *(uint4*)(dst + 8)  = *(const uint4*)(src + 8);
      *(uint4*)(dst + 16) = *(const uint4*)(src + 16);
      *(uint4*)(dst + 24) = *(const uint4*)(src + 24);
    }
    __syncthreads();
    #pragma unroll
    for (int ks = 0; ks < 2; ++ks){
      int m0 = ks*32 + quad*8;
      s16x8 afs[2], bfp[4];
      #pragma unroll
      for (int i = 0; i < 2; ++i) afs[i] = *(s16x8*)&spasT[(2*w+i)*16 + lm][m0];
      #pragma unroll
      for (int rt = 0; rt < 4; ++rt) bfp[rt] = *(s16x8*)&Ps[rt*16 + lm][mc2*64 + m0];
      #pragma unroll
      for (int i = 0; i < 2; ++i)
        #pragma unroll
        for (int rt = 0; rt < 4; ++rt)
          acc2[i][rt] = __builtin_amdgcn_mfma_f32_16x16x32_bf16(afs[i], bfp[rt], acc2[i][rt], 0, 0, 0);
    }
  }
  // store: D row=d(quad*4+reg), col=row(lm); +I term direct (spa pre-activated)
  #pragma unroll
  for (int i = 0; i < 2; ++i){
    int d0 = (2*w+i)*16 + quad*4;
    #pragma unroll
    for (int rt = 0; rt < 4; ++rt){
      int grow = bp*256 + nt*64 + rt*16 + lm;
      uint2 sp = *(const uint2*)&spa[grow*128 + d0];
      f4 a = acc2[i][rt];
      a.x += b2f((u16)(sp.x & 0xffff)); a.y += b2f((u16)(sp.x >> 16));
      a.z += b2f((u16)(sp.y & 0xffff)); a.w += b2f((u16)(sp.y >> 16));
      uint2 p; p.x = pk(a.x, a.y); p.y = pk(a.z, a.w);
      *(uint2*)&agg[grow*128 + d0] = p;
    }
  }
}

// ---------------- cooperative gemm1: theta GEMM + global BN-stat sync + fused BN+lrelu ----------------
// grid MUST be 1024, block 256, launch_bounds(256,4): 4 blocks/CU x 256 CU = 1024 co-resident.
// Barrier: increment once via RMW; poll via plain coherent atomic LOAD (no RMW congestion).
__global__ __launch_bounds__(256, 4) void k_gemm1c(const u16* __restrict__ A,
                                                   const float* __restrict__ bvec,
                                                   const float* __restrict__ g,
                                                   const float* __restrict__ bta,
                                                   float* __restrict__ outp){
  __shared__ __align__(16) u16 As[64][136];       // 17408 B
  __shared__ __align__(16) u16 stash[64][132];    // 16896 B (tile0 pre-BN, bf16, 2-dword skew)
  __shared__ float sbS[2][128];                   // 1024 B   -> total 35328 <= 40960
  const u16* Wh = &g_wqh[0][0];
  const u16* Wl = &g_wql[0][0];
  const int bid = blockIdx.x;
  const int tid = threadIdx.x;
  const int w = tid >> 6, l = tid & 63, quad = l >> 4, lm = l & 15;

  f4 o1[2][4];                                    // tile1 pre-BN stays in regs
  f4 sv[2] = {(f4)0.f, (f4)0.f}, qv[2] = {(f4)0.f, (f4)0.f};

  #pragma unroll
  for (int ti = 0; ti < 2; ++ti){
    const int rowbase = bid*128 + ti*64;
    f4 acc[2][4];
    #pragma unroll
    for (int i = 0; i < 2; ++i)
      #pragma unroll
      for (int rt = 0; rt < 4; ++rt) acc[i][rt] = (f4)0.f;

    if (ti) __syncthreads();                       // As reads of tile0 done before restage
    { int r = tid >> 2, c0 = (tid & 3)*32;
      #pragma unroll
      for (int j = 0; j < 4; ++j)
        *(uint4*)&As[r][c0 + 8*j] = *(const uint4*)&A[(rowbase + r)*128 + c0 + 8*j];
    }
    __syncthreads();

    #pragma unroll
    for (int s = 0; s < 4; ++s){
      int k0 = s*32 + quad*8;
      s16x8 awh[2], awl[2], ba[4];
      #pragma unroll
      for (int i = 0; i < 2; ++i){
        awh[i] = *(const s16x8*)&Wh[((2*w+i)*16 + lm)*128 + k0];
        awl[i] = *(const s16x8*)&Wl[((2*w+i)*16 + lm)*128 + k0];
      }
      #pragma unroll
      for (int rt = 0; rt < 4; ++rt) ba[rt] = *(s16x8*)&As[rt*16 + lm][k0];
      #pragma unroll
      for (int i = 0; i < 2; ++i)
        #pragma unroll
        for (int rt = 0; rt < 4; ++rt){
          acc[i][rt] = __builtin_amdgcn_mfma_f32_16x16x32_bf16(awh[i], ba[rt], acc[i][rt], 0, 0, 0);
          acc[i][rt] = __builtin_amdgcn_mfma_f32_16x16x32_bf16(awl[i], ba[rt], acc[i][rt], 0, 0, 0);
        }
    }
    // bias + stats; tile0 -> LDS stash (bf16), tile1 stays in regs
    #pragma unroll
    for (int i = 0; i < 2; ++i){
      int e0 = (2*w+i)*16 + quad*4;
      f4 bv = *(const f4*)&bvec[e0];
      #pragma unroll
      for (int rt = 0; rt < 4; ++rt){
        f4 o = acc[i][rt] + bv;
        if (ti == 0){
          uint2 p; p.x = pk(o.x, o.y); p.y = pk(o.z, o.w);
          *(uint2*)&stash[rt*16 + lm][e0] = p;
        } else {
          o1[i][rt] = o;
        }
        sv[i] += o; qv[i] += o*o;
      }
    }
  }

  // lane-reduce stats over lm, atomic into g_stats[2]
  #pragma unroll
  for (int i = 0; i < 2; ++i){
    #pragma unroll
    for (int m = 1; m < 16; m <<= 1){
      sv[i].x+=__shfl_xor(sv[i].x,m); sv[i].y+=__shfl_xor(sv[i].y,m);
      sv[i].z+=__shfl_xor(sv[i].z,m); sv[i].w+=__shfl_xor(sv[i].w,m);
      qv[i].x+=__shfl_xor(qv[i].x,m); qv[i].y+=__shfl_xor(qv[i].y,m);
      qv[i].z+=__shfl_xor(qv[i].z,m); qv[i].w+=__shfl_xor(qv[i].w,m);
    }
    if (lm == 0){
      int e0 = (2*w+i)*16 + quad*4;
      atomicAdd(&g_stats[2][0][e0+0], sv[i].x); atomicAdd(&g_stats[2][0][e0+1], sv[i].y);
      atomicAdd(&g_stats[2][0][e0+2], sv[i].z); atomicAdd(&g_stats[2][0][e0+3], sv[i].w);
      atomicAdd(&g_stats[2][1][e0+0], qv[i].x); atomicAdd(&g_stats[2][1][e0+1], qv[i].y);
      atomicAdd(&g_stats[2][1][e0+2], qv[i].z); atomicAdd(&g_stats[2][1][e0+3], qv[i].w);
    }
  }
  __threadfence();
  __syncthreads();
  if (tid == 0){
    __hip_atomic_fetch_add(&g_cnt[2], 1, __ATOMIC_ACQ_REL, __HIP_MEMORY_SCOPE_AGENT);
    while (__hip_atomic_load(&g_cnt[2], __ATOMIC_ACQUIRE, __HIP_MEMORY_SCOPE_AGENT) < 1024)
      __builtin_amdgcn_s_sleep(32);
  }
  __syncthreads();
  // finalize scale/bias (coherent atomic loads)
  if (tid < 128){
    float sm = __hip_atomic_load(&g_stats[2][0][tid], __ATOMIC_RELAXED, __HIP_MEMORY_SCOPE_AGENT);
    float sq = __hip_atomic_load(&g_stats[2][1][tid], __ATOMIC_RELAXED, __HIP_MEMORY_SCOPE_AGENT);
    float mean = sm * INV_CNT;
    float var  = sq * INV_CNT - mean*mean;
    float sc = g[tid] * rsqrtf(var + EPSB);
    sbS[0][tid] = sc;
    sbS[1][tid] = bta[tid] - mean*sc;
  }
  __syncthreads();
  // apply BN + lrelu, write final fp32
  #pragma unroll
  for (int i = 0; i < 2; ++i){
    int e0 = (2*w+i)*16 + quad*4;
    f4 sc = *(const f4*)&sbS[0][e0];
    f4 bi = *(const f4*)&sbS[1][e0];
    #pragma unroll
    for (int rt = 0; rt < 4; ++rt){
      // tile0 from stash (bf16-rounded pre-BN)
      uint2 p = *(const uint2*)&stash[rt*16 + lm][e0];
      f4 t0;
      t0.x = b2f((u16)(p.x & 0xffff)); t0.y = b2f((u16)(p.x >> 16));
      t0.z = b2f((u16)(p.y & 0xffff)); t0.w = b2f((u16)(p.y >> 16));
      f4 r0;
      r0.x = lrelu(fmaf(t0.x, sc.x, bi.x)); r0.y = lrelu(fmaf(t0.y, sc.y, bi.y));
      r0.z = lrelu(fmaf(t0.z, sc.z, bi.z)); r0.w = lrelu(fmaf(t0.w, sc.w, bi.w));
      *(f4*)&outp[(bid*128 + rt*16 + lm)*128 + e0] = r0;
      // tile1 from regs (exact fp32 pre-BN)
      f4 o = o1[i][rt];
      f4 r1;
      r1.x = lrelu(fmaf(o.x, sc.x, bi.x)); r1.y = lrelu(fmaf(o.y, sc.y, bi.y));
      r1.z = lrelu(fmaf(o.z, sc.z, bi.z)); r1.w = lrelu(fmaf(o.w, sc.w, bi.w));
      *(f4*)&outp[(bid*128 + 64 + rt*16 + lm)*128 + e0] = r1;
    }
  }
}

extern "C" void kernel_launch(void* const* d_in, const int* in_sizes, int n_in,
                              void* d_out, int out_size, void* d_ws, size_t ws_size,
                              hipStream_t stream) {
  const float* x    = (const float*)d_in[0];
  const float* w1   = (const float*)d_in[1];
  const float* bn1g = (const float*)d_in[2];
  const float* bn1b = (const float*)d_in[3];
  const float* w2   = (const float*)d_in[4];
  const float* bn2g = (const float*)d_in[5];
  const float* bn2b = (const float*)d_in[6];
  const float* mapw = (const float*)d_in[7];
  const float* mapb = (const float*)d_in[8];
  const float* thw  = (const float*)d_in[9];
  const float* thb  = (const float*)d_in[10];
  const float* bnSg = (const float*)d_in[11];
  const float* bnSb = (const float*)d_in[12];
  float* outp = (float*)d_out;

  // ws (64 MB): spa (16M bf16; pre-BN2 until gemm0 activates in place) + agg (16M bf16)
  u16* spa = (u16*)d_ws;
  u16* agg = spa + 16777216;

  // d_out scratch phases: y1 fp32 (64 MB) -> mapped hi/lo planes (mh 32MB + ml 32MB) -> out fp32
  float* y1f = (float*)d_out;
  u16* mh    = (u16*)d_out;

  k_prepw<<<416, 256, 0, stream>>>(w1, w2, mapw, thw);
  k_conv1<<<2048, 256, 0, stream>>>(x, y1f);
  k_reduce<<<16, 256, 0, stream>>>(bn1g, bn1b, 0);
  k_conv2<<<2048, 256, 0, stream>>>(y1f, spa);
  k_reduce<<<16, 256, 0, stream>>>(bn2g, bn2b, 1);
  k_gemm0<<<2048, 256, 0, stream>>>(spa, spa, mapb, mh);
  k_adjagg<<<2048, 256, 0, stream>>>(mh, mh + 16777216, spa, agg);
  k_gemm1c<<<1024, 256, 0, stream>>>(agg, thb, bnSg, bnSb, outp);
}

// Round 9
// 393.628 us; speedup vs baseline: 1.7588x; 1.6726x over previous
//
#include <hip/hip_runtime.h>

#define SLOPE 0.01f
#define EPSB 1e-5f
#define INV_CNT (1.0f/131072.0f)

typedef unsigned short u16;
typedef unsigned int u32;
typedef __attribute__((ext_vector_type(8))) short s16x8;
typedef __attribute__((ext_vector_type(4))) float f4;

__device__ float g_stats[3][2][128];   // [which][sum|sq][channel]
__device__ float g_sb[3][2][128];      // [which][scale|bias][channel]
__device__ float g_part[2048][256];    // per-block partial stats [block][sum128|sq128]
__device__ int   g_cnt[3];             // completion counters
__device__ u16 g_w1h[3][128][64];      // [k][co][ci] hi
__device__ u16 g_w1l[3][128][64];      // lo
__device__ u16 g_w2h[3][128][128];
__device__ u16 g_w2l[3][128][128];
__device__ u16 g_wmh[128][128];        // [e][d]
__device__ u16 g_wml[128][128];
__device__ u16 g_wqh[128][128];        // theta
__device__ u16 g_wql[128][128];

__device__ __forceinline__ float lrelu(float x){ return x > 0.f ? x : SLOPE*x; }
__device__ __forceinline__ u16 f2b(float f){
  u32 u = __float_as_uint(f);
  return (u16)((u + 0x7fffu + ((u >> 16) & 1u)) >> 16);   // RNE
}
__device__ __forceinline__ float b2f(u16 h){ return __uint_as_float(((u32)h) << 16); }
__device__ __forceinline__ u32 pk(float a, float b){ return (u32)f2b(a) | ((u32)f2b(b) << 16); }

// ---------------- prep: zero stats/counters + fp32 weights -> bf16 hi/lo ----------------
__global__ void k_prepw(const float* __restrict__ w1, const float* __restrict__ w2,
                        const float* __restrict__ mapw, const float* __restrict__ thw){
  int idx = blockIdx.x*256 + threadIdx.x;
  if (idx < 768) ((float*)g_stats)[idx] = 0.f;
  if (idx < 3) g_cnt[idx] = 0;
  if (idx < 24576){
    int kk = idx >> 13, r = idx & 8191, co = r >> 6, ci = r & 63;
    float v = w1[co*192 + ci*3 + kk];
    u16 h = f2b(v);
    g_w1h[kk][co][ci] = h; g_w1l[kk][co][ci] = f2b(v - b2f(h));
  } else if (idx < 73728){
    int j = idx - 24576;
    int kk = j >> 14, r = j & 16383, co = r >> 7, ci = r & 127;
    float v = w2[co*384 + ci*3 + kk];
    u16 h = f2b(v);
    g_w2h[kk][co][ci] = h; g_w2l[kk][co][ci] = f2b(v - b2f(h));
  } else if (idx < 90112){
    int j = idx - 73728;
    float v = mapw[j];
    u16 h = f2b(v);
    ((u16*)g_wmh)[j] = h; ((u16*)g_wml)[j] = f2b(v - b2f(h));
  } else if (idx < 106496){
    int j = idx - 90112;
    float v = thw[j];
    u16 h = f2b(v);
    ((u16*)g_wqh)[j] = h; ((u16*)g_wql)[j] = f2b(v - b2f(h));
  }
}

// ---------------- reduce partials -> g_stats; last block finalizes scale/bias ----------------
__global__ void k_reduce(const float* __restrict__ g, const float* __restrict__ bta, int which){
  const float* base = &g_part[blockIdx.x*128][0];
  int j = threadIdx.x;
  float s = 0.f;
  #pragma unroll 4
  for (int r = 0; r < 128; ++r) s += base[r*256 + j];
  atomicAdd(&((float*)g_stats)[which*256 + j], s);
  __threadfence();
  __shared__ int lastf;
  __syncthreads();
  if (threadIdx.x == 0) lastf = (atomicAdd(&g_cnt[which], 1) == 15) ? 1 : 0;
  __syncthreads();
  if (lastf){
    __threadfence();
    if (j < 128){
      float sm = atomicAdd(&g_stats[which][0][j], 0.f);   // coherent read
      float sq = atomicAdd(&g_stats[which][1][j], 0.f);
      float mean = sm * INV_CNT;
      float var  = sq * INV_CNT - mean*mean;
      float sc = g[j] * rsqrtf(var + EPSB);
      g_sb[which][0][j] = sc;
      g_sb[which][1][j] = bta[j] - mean*sc;
    }
  }
}

// ---------------- conv1 MFMA: weights direct-from-L2, 1 barrier; y1 stored bf16 (pre-BN1) ----------------
__global__ __launch_bounds__(256, 4) void k_conv1(const float* __restrict__ x, u16* __restrict__ y1b){
  __shared__ __align__(16) u16 a0h[2][34][72];
  __shared__ __align__(16) u16 a0l[2][34][72];
  const int bid = blockIdx.x;
  const int bn0 = bid*2;
  const int b = bn0 >> 8, n = bn0 & 255;
  const int tid = threadIdx.x;
  const int w = tid >> 6, l = tid & 63, quad = l >> 4, lm = l & 15;
  f4 acc[2][4];
  #pragma unroll
  for (int i = 0; i < 2; ++i)
    #pragma unroll
    for (int j = 0; j < 4; ++j) acc[i][j] = (f4)0.f;

  { // stage x -> a0h/a0l (hi/lo bf16), transposed to [t][ci]
    int nn = tid >> 7, rem = tid & 127, t = rem >> 2, ci0 = (rem & 3)*16;
    const float* px = x + ((b*32 + t)*256 + n + nn)*64 + ci0;
    u16 hh[16], ll[16];
    #pragma unroll
    for (int j = 0; j < 4; ++j){
      float4 v = *(const float4*)(px + 4*j);
      float vv[4] = {v.x, v.y, v.z, v.w};
      #pragma unroll
      for (int e = 0; e < 4; ++e){
        u16 h = f2b(vv[e]);
        hh[4*j+e] = h; ll[4*j+e] = f2b(vv[e] - b2f(h));
      }
    }
    *(uint4*)&a0h[nn][t+1][ci0]   = *(uint4*)&hh[0];
    *(uint4*)&a0h[nn][t+1][ci0+8] = *(uint4*)&hh[8];
    *(uint4*)&a0l[nn][t+1][ci0]   = *(uint4*)&ll[0];
    *(uint4*)&a0l[nn][t+1][ci0+8] = *(uint4*)&ll[8];
  }
  for (int u = tid; u < 288; u += 256){
    int a = u / 144, rr = u % 144, r = rr / 36, cw = rr % 36;
    u32* base = a ? (u32*)&a0l[r>>1][(r&1)*33][0] : (u32*)&a0h[r>>1][(r&1)*33][0];
    base[cw] = 0u;
  }
  __syncthreads();

  for (int kk = 0; kk < 3; ++kk){
    #pragma unroll
    for (int s = 0; s < 2; ++s){
      int ci0 = s*32 + quad*8;
      s16x8 wh[2], wl[2], bh[4], bl[4];
      #pragma unroll
      for (int i = 0; i < 2; ++i){
        wh[i] = *(const s16x8*)&g_w1h[kk][(2*w+i)*16 + lm][ci0];
        wl[i] = *(const s16x8*)&g_w1l[kk][(2*w+i)*16 + lm][ci0];
      }
      #pragma unroll
      for (int nt = 0; nt < 4; ++nt){
        bh[nt] = *(s16x8*)&a0h[nt>>1][(nt&1)*16 + lm + kk][ci0];
        bl[nt] = *(s16x8*)&a0l[nt>>1][(nt&1)*16 + lm + kk][ci0];
      }
      #pragma unroll
      for (int i = 0; i < 2; ++i)
        #pragma unroll
        for (int nt = 0; nt < 4; ++nt){
          acc[i][nt] = __builtin_amdgcn_mfma_f32_16x16x32_bf16(wh[i], bh[nt], acc[i][nt], 0, 0, 0);
          acc[i][nt] = __builtin_amdgcn_mfma_f32_16x16x32_bf16(wh[i], bl[nt], acc[i][nt], 0, 0, 0);
          acc[i][nt] = __builtin_amdgcn_mfma_f32_16x16x32_bf16(wl[i], bh[nt], acc[i][nt], 0, 0, 0);
        }
    }
  }
  // epilogue: D row=co(quad*4+reg), col=t(lm). Store bf16 (pre-BN1); stats from exact fp32.
  #pragma unroll
  for (int i = 0; i < 2; ++i){
    int co0 = (2*w+i)*16 + quad*4;
    float s0=0,s1=0,s2=0,s3=0,q0=0,q1=0,q2=0,q3=0;
    #pragma unroll
    for (int nt = 0; nt < 4; ++nt){
      f4 a = acc[i][nt];
      int nn = nt >> 1, t = (nt & 1)*16 + lm;
      uint2 p; p.x = pk(a.x, a.y); p.y = pk(a.z, a.w);
      *(uint2*)&y1b[((bn0+nn)*32 + t)*128 + co0] = p;
      s0+=a.x; s1+=a.y; s2+=a.z; s3+=a.w;
      q0+=a.x*a.x; q1+=a.y*a.y; q2+=a.z*a.z; q3+=a.w*a.w;
    }
    #pragma unroll
    for (int m = 1; m < 16; m <<= 1){
      s0+=__shfl_xor(s0,m); s1+=__shfl_xor(s1,m); s2+=__shfl_xor(s2,m); s3+=__shfl_xor(s3,m);
      q0+=__shfl_xor(q0,m); q1+=__shfl_xor(q1,m); q2+=__shfl_xor(q2,m); q3+=__shfl_xor(q3,m);
    }
    if (lm == 0){
      f4 sv = {s0,s1,s2,s3}, qv = {q0,q1,q2,q3};
      *(f4*)&g_part[bid][co0]       = sv;
      *(f4*)&g_part[bid][128 + co0] = qv;
    }
  }
}

// ---------------- conv2 MFMA: weights direct-from-L2, 1 barrier; y1 read bf16 ----------------
__global__ __launch_bounds__(256, 4) void k_conv2(const u16* __restrict__ y1b, u16* __restrict__ spa){
  __shared__ __align__(16) u16 a1s[2][34][136];
  const int bid = blockIdx.x;
  const int bn0 = bid*2;
  const int b = bn0 >> 8, n = bn0 & 255;
  const int tid = threadIdx.x;
  const int w = tid >> 6, l = tid & 63, quad = l >> 4, lm = l & 15;
  f4 acc2[4][2];
  #pragma unroll
  for (int mt = 0; mt < 4; ++mt)
    #pragma unroll
    for (int i = 0; i < 2; ++i) acc2[mt][i] = (f4)0.f;

  { // stage bn1+relu(y1 bf16) -> a1s
    int nn = tid >> 7, rem = tid & 127, t = rem >> 2, ci0 = (rem & 3)*32;
    const u16* py = y1b + ((bn0+nn)*32 + t)*128;
    #pragma unroll
    for (int j = 0; j < 4; ++j){
      uint4 v = *(const uint4*)(py + ci0 + 8*j);
      u32 vv[4] = {v.x, v.y, v.z, v.w};
      u16 oo[8];
      #pragma unroll
      for (int e = 0; e < 4; ++e){
        int ci = ci0 + 8*j + 2*e;
        oo[2*e]   = f2b(fmaxf(fmaf(b2f((u16)(vv[e] & 0xffff)), g_sb[0][0][ci],   g_sb[0][1][ci]),   0.f));
        oo[2*e+1] = f2b(fmaxf(fmaf(b2f((u16)(vv[e] >> 16)),    g_sb[0][0][ci+1], g_sb[0][1][ci+1]), 0.f));
      }
      *(uint4*)&a1s[nn][t+1][ci0 + 8*j] = *(uint4*)&oo[0];
    }
  }
  for (int u = tid; u < 272; u += 256){
    int r = u/68, cw = u%68;
    ((u32*)&a1s[r>>1][(r&1)*33][0])[cw] = 0u;
  }
  __syncthreads();

  for (int kk = 0; kk < 3; ++kk){
    #pragma unroll
    for (int s = 0; s < 4; ++s){
      int ci0 = s*32 + quad*8;
      s16x8 ax[4], bwh[2], bwl[2];
      #pragma unroll
      for (int i = 0; i < 2; ++i){
        bwh[i] = *(const s16x8*)&g_w2h[kk][(2*w+i)*16 + lm][ci0];
        bwl[i] = *(const s16x8*)&g_w2l[kk][(2*w+i)*16 + lm][ci0];
      }
      #pragma unroll
      for (int mt = 0; mt < 4; ++mt) ax[mt] = *(s16x8*)&a1s[mt>>1][(mt&1)*16 + lm + kk][ci0];
      #pragma unroll
      for (int mt = 0; mt < 4; ++mt)
        #pragma unroll
        for (int i = 0; i < 2; ++i){
          acc2[mt][i] = __builtin_amdgcn_mfma_f32_16x16x32_bf16(ax[mt], bwh[i], acc2[mt][i], 0, 0, 0);
          acc2[mt][i] = __builtin_amdgcn_mfma_f32_16x16x32_bf16(ax[mt], bwl[i], acc2[mt][i], 0, 0, 0);
        }
    }
  }
  // epilogue: D row=t(quad*4+reg), col=co(lm); permuted spa store (pre-BN2), partial stats
  #pragma unroll
  for (int i = 0; i < 2; ++i){
    int co = (2*w+i)*16 + lm;
    float s = 0.f, q = 0.f;
    #pragma unroll
    for (int mt = 0; mt < 4; ++mt){
      f4 a = acc2[mt][i];
      int off0 = co*32 + (mt&1)*16 + quad*4;       // off = co*32 + t
      int tp = off0 >> 7, cp = off0 & 127;
      int row = (b*32 + tp)*256 + (n + (mt>>1));
      uint2 p; p.x = pk(a.x, a.y); p.y = pk(a.z, a.w);
      *(uint2*)&spa[row*128 + cp] = p;
      s += a.x + a.y + a.z + a.w;
      q += a.x*a.x + a.y*a.y + a.z*a.z + a.w*a.w;
    }
    s += __shfl_xor(s, 16); s += __shfl_xor(s, 32);
    q += __shfl_xor(q, 16); q += __shfl_xor(q, 32);
    if (l < 16){
      g_part[bid][co]       = s;
      g_part[bid][128 + co] = q;
    }
  }
}

// ---------------- gemm0 (map) MFMA: BN2+relu inline; write-back activated spa; mapped hi/lo planes ----------------
__global__ __launch_bounds__(256, 4) void k_gemm0(const u16* A,
                                                  u16* spaw,
                                                  const float* __restrict__ bvec,
                                                  u16* __restrict__ mh){
  __shared__ __align__(16) u16 As[64][136];
  const u16* Wh = &g_wmh[0][0];
  const u16* Wl = &g_wml[0][0];
  const int bid = blockIdx.x;
  const int rowbase = bid * 64;
  const int tid = threadIdx.x;
  const int w = tid >> 6, l = tid & 63, quad = l >> 4, lm = l & 15;
  f4 acc[2][4];
  #pragma unroll
  for (int i = 0; i < 2; ++i)
    #pragma unroll
    for (int rt = 0; rt < 4; ++rt) acc[i][rt] = (f4)0.f;

  { int r = tid >> 2, c0 = (tid & 3)*32;
    int row = rowbase + r;
    // fused BN2+relu: channel = tp*4 + chunk, tp = (row>>8)&31, chunk = tid&3
    int c = ((row >> 8) & 31)*4 + (tid & 3);
    float sc = g_sb[1][0][c], bi = g_sb[1][1][c];
    #pragma unroll
    for (int j = 0; j < 4; ++j){
      uint4 v = *(const uint4*)&A[row*128 + c0 + 8*j];
      u32 vv[4] = {v.x, v.y, v.z, v.w};
      u16 oo[8];
      #pragma unroll
      for (int e = 0; e < 4; ++e){
        oo[2*e]   = f2b(fmaxf(fmaf(b2f((u16)(vv[e] & 0xffff)), sc, bi), 0.f));
        oo[2*e+1] = f2b(fmaxf(fmaf(b2f((u16)(vv[e] >> 16)),    sc, bi), 0.f));
      }
      uint4 ov = *(uint4*)&oo[0];
      *(uint4*)&As[r][c0 + 8*j] = ov;
      *(uint4*)&spaw[row*128 + c0 + 8*j] = ov;   // activated write-back
    }
  }
  __syncthreads();

  #pragma unroll
  for (int s = 0; s < 4; ++s){
    int k0 = s*32 + quad*8;
    s16x8 awh[2], awl[2], ba[4];
    #pragma unroll
    for (int i = 0; i < 2; ++i){
      awh[i] = *(const s16x8*)&Wh[((2*w+i)*16 + lm)*128 + k0];
      awl[i] = *(const s16x8*)&Wl[((2*w+i)*16 + lm)*128 + k0];
    }
    #pragma unroll
    for (int rt = 0; rt < 4; ++rt) ba[rt] = *(s16x8*)&As[rt*16 + lm][k0];
    #pragma unroll
    for (int i = 0; i < 2; ++i)
      #pragma unroll
      for (int rt = 0; rt < 4; ++rt){
        acc[i][rt] = __builtin_amdgcn_mfma_f32_16x16x32_bf16(awh[i], ba[rt], acc[i][rt], 0, 0, 0);
        acc[i][rt] = __builtin_amdgcn_mfma_f32_16x16x32_bf16(awl[i], ba[rt], acc[i][rt], 0, 0, 0);
      }
  }
  // epilogue: hi/lo planes, chunked [bp][dc][m][32]
  #pragma unroll
  for (int i = 0; i < 2; ++i){
    int e0 = (2*w+i)*16 + quad*4;
    f4 bv = *(const f4*)&bvec[e0];
    u16* ml = mh + 16777216;
    int dc = e0 >> 5, ec = e0 & 31;
    #pragma unroll
    for (int rt = 0; rt < 4; ++rt){
      int row = rowbase + rt*16 + lm;
      int bp = row >> 8, m = row & 255;
      f4 o = acc[i][rt] + bv;
      float fv[4] = {o.x, o.y, o.z, o.w};
      u16 hh[4], ll[4];
      #pragma unroll
      for (int e = 0; e < 4; ++e){
        u16 h = f2b(fv[e]);
        hh[e] = h; ll[e] = f2b(fv[e] - b2f(h));
      }
      int off = ((bp*4 + dc)*256 + m)*32 + ec;
      *(uint2*)&mh[off] = *(uint2*)&hh[0];
      *(uint2*)&ml[off] = *(uint2*)&ll[0];
    }
  }
}

// ---------------- fused adj+agg MFMA; spa pre-activated; in-LDS conflict-free transpose ----------------
__global__ __launch_bounds__(256) void k_adjagg(const u16* __restrict__ mh,
                                                const u16* __restrict__ ml,
                                                const u16* __restrict__ spa,
                                                u16* __restrict__ agg){
  __shared__ __align__(16) char smem[52224];
  u16 (*mbh)[40]   = (u16(*)[40])(smem);
  u16 (*mbl)[40]   = (u16(*)[40])(smem + 20480);
  u16 (*Ps)[264]   = (u16(*)[264])(smem);            // [64][264] = 33792 B
  u16 (*spasT)[72] = (u16(*)[72])(smem + 33792);     // [128][72] = 18432 B
  // XCD-aware remap: 4 nt-blocks of one bp land consecutively on the same XCD
  const int rb = blockIdx.x;
  const int vb = (rb & 7)*256 + (rb >> 3);
  const int bp = vb >> 2;
  const int nt = vb & 3;
  const int tid = threadIdx.x;
  const int w = tid >> 6, l = tid & 63, quad = l >> 4, lm = l & 15;

  // ---- phase 1: S rows (wave w -> row-tile w) x all 256 cols, hi/lo 3-term ----
  f4 sacc[16];
  #pragma unroll
  for (int ct = 0; ct < 16; ++ct) sacc[ct] = (f4)0.f;

  for (int dc = 0; dc < 4; ++dc){
    __syncthreads();
    { // pure copy staging from pre-split chunked planes (coalesced, conflict-free)
      const u16* srch = mh + ((bp*4 + dc) << 13);
      const u16* srcl = ml + ((bp*4 + dc) << 13);
      int m0 = tid >> 2, seg = (tid & 3)*8;
      #pragma unroll
      for (int r = 0; r < 4; ++r){
        int m = m0 + r*64;
        *(uint4*)&mbh[m][seg] = *(const uint4*)&srch[m*32 + seg];
        *(uint4*)&mbl[m][seg] = *(const uint4*)&srcl[m*32 + seg];
      }
    }
    __syncthreads();
    s16x8 amh = *(s16x8*)&mbh[nt*64 + w*16 + lm][quad*8];
    s16x8 aml = *(s16x8*)&mbl[nt*64 + w*16 + lm][quad*8];
    #pragma unroll
    for (int ct = 0; ct < 16; ++ct){
      s16x8 bmh = *(s16x8*)&mbh[ct*16 + lm][quad*8];
      s16x8 bml = *(s16x8*)&mbl[ct*16 + lm][quad*8];
      sacc[ct] = __builtin_amdgcn_mfma_f32_16x16x32_bf16(amh, bmh, sacc[ct], 0, 0, 0);
      sacc[ct] = __builtin_amdgcn_mfma_f32_16x16x32_bf16(amh, bml, sacc[ct], 0, 0, 0);
      sacc[ct] = __builtin_amdgcn_mfma_f32_16x16x32_bf16(aml, bmh, sacc[ct], 0, 0, 0);
    }
  }
  __syncthreads();   // all mbuf reads done; Ps may now overlay

  // ---- softmax (regs only) -> Ps[row][m] bf16 ----
  #pragma unroll
  for (int r = 0; r < 4; ++r){
    int rowg = nt*64 + w*16 + quad*4 + r;
    float v[16]; float mx = -3.0e38f;
    #pragma unroll
    for (int ct = 0; ct < 16; ++ct){
      float t = sacc[ct][r];
      if (ct*16 + lm == rowg) t -= 1e8f;
      t = lrelu(t);
      v[ct] = t; mx = fmaxf(mx, t);
    }
    #pragma unroll
    for (int m = 1; m < 16; m <<= 1) mx = fmaxf(mx, __shfl_xor(mx, m));
    float sum = 0.f;
    #pragma unroll
    for (int ct = 0; ct < 16; ++ct){ float e = __expf(v[ct] - mx); v[ct] = e; sum += e; }
    #pragma unroll
    for (int m = 1; m < 16; m <<= 1) sum += __shfl_xor(sum, m);
    float inv = 1.0f / sum;
    #pragma unroll
    for (int ct = 0; ct < 16; ++ct)
      Ps[w*16 + quad*4 + r][ct*16 + lm] = f2b(v[ct] * inv);
  }

  // ---- phase 2: agg = P @ spa (+ spa for +I). spa pre-activated; pure copy transpose. ----
  f4 acc2[2][4];
  #pragma unroll
  for (int i = 0; i < 2; ++i)
    #pragma unroll
    for (int rt = 0; rt < 4; ++rt) acc2[i][rt] = (f4)0.f;

  for (int mc2 = 0; mc2 < 4; ++mc2){
    __syncthreads();
    { // transpose-stage spa[64 m][128 d] -> spasT[128][72]
      int mlo = tid & 63;
      int db = (tid >> 6)*8;
      const u16* ps = spa + (bp*256 + mc2*64 + mlo)*128;
      #pragma unroll
      for (int r = 0; r < 4; ++r){
        int d0 = db + r*32;
        uint4 v = *(const uint4*)(ps + d0);
        u16 h[8]; *(uint4*)&h[0] = v;
        #pragma unroll
        for (int j = 0; j < 8; ++j) spasT[d0+j][mlo] = h[j];
      }
    }
    __syncthreads();
    #pragma unroll
    for (int ks = 0; ks < 2; ++ks){
      int m0 = ks*32 + quad*8;
      s16x8 afs[2], bfp[4];
      #pragma unroll
      for (int i = 0; i < 2; ++i) afs[i] = *(s16x8*)&spasT[(2*w+i)*16 + lm][m0];
      #pragma unroll
      for (int rt = 0; rt < 4; ++rt) bfp[rt] = *(s16x8*)&Ps[rt*16 + lm][mc2*64 + m0];
      #pragma unroll
      for (int i = 0; i < 2; ++i)
        #pragma unroll
        for (int rt = 0; rt < 4; ++rt)
          acc2[i][rt] = __builtin_amdgcn_mfma_f32_16x16x32_bf16(afs[i], bfp[rt], acc2[i][rt], 0, 0, 0);
    }
  }
  // store: D row=d(quad*4+reg), col=row(lm); +I term direct (spa pre-activated)
  #pragma unroll
  for (int i = 0; i < 2; ++i){
    int d0 = (2*w+i)*16 + quad*4;
    #pragma unroll
    for (int rt = 0; rt < 4; ++rt){
      int grow = bp*256 + nt*64 + rt*16 + lm;
      uint2 sp = *(const uint2*)&spa[grow*128 + d0];
      f4 a = acc2[i][rt];
      a.x += b2f((u16)(sp.x & 0xffff)); a.y += b2f((u16)(sp.x >> 16));
      a.z += b2f((u16)(sp.y & 0xffff)); a.w += b2f((u16)(sp.y >> 16));
      uint2 p; p.x = pk(a.x, a.y); p.y = pk(a.z, a.w);
      *(uint2*)&agg[grow*128 + d0] = p;
    }
  }
}

// ---------------- gemm1 (theta) MFMA: bf16 out_pre + exact-fp32 stats partials ----------------
__global__ __launch_bounds__(256, 4) void k_gemm1(const u16* __restrict__ A,
                                                  const float* __restrict__ bvec,
                                                  u16* __restrict__ outpre){
  __shared__ __align__(16) u16 As[64][136];
  const u16* Wh = &g_wqh[0][0];
  const u16* Wl = &g_wql[0][0];
  const int bid = blockIdx.x;
  const int rowbase = bid * 64;
  const int tid = threadIdx.x;
  const int w = tid >> 6, l = tid & 63, quad = l >> 4, lm = l & 15;
  f4 acc[2][4];
  #pragma unroll
  for (int i = 0; i < 2; ++i)
    #pragma unroll
    for (int rt = 0; rt < 4; ++rt) acc[i][rt] = (f4)0.f;

  { int r = tid >> 2, c0 = (tid & 3)*32;
    #pragma unroll
    for (int j = 0; j < 4; ++j)
      *(uint4*)&As[r][c0 + 8*j] = *(const uint4*)&A[(rowbase + r)*128 + c0 + 8*j];
  }
  __syncthreads();

  #pragma unroll
  for (int s = 0; s < 4; ++s){
    int k0 = s*32 + quad*8;
    s16x8 awh[2], awl[2], ba[4];
    #pragma unroll
    for (int i = 0; i < 2; ++i){
      awh[i] = *(const s16x8*)&Wh[((2*w+i)*16 + lm)*128 + k0];
      awl[i] = *(const s16x8*)&Wl[((2*w+i)*16 + lm)*128 + k0];
    }
    #pragma unroll
    for (int rt = 0; rt < 4; ++rt) ba[rt] = *(s16x8*)&As[rt*16 + lm][k0];
    #pragma unroll
    for (int i = 0; i < 2; ++i)
      #pragma unroll
      for (int rt = 0; rt < 4; ++rt){
        acc[i][rt] = __builtin_amdgcn_mfma_f32_16x16x32_bf16(awh[i], ba[rt], acc[i][rt], 0, 0, 0);
        acc[i][rt] = __builtin_amdgcn_mfma_f32_16x16x32_bf16(awl[i], ba[rt], acc[i][rt], 0, 0, 0);
      }
  }
  // epilogue: D row=e(quad*4+reg), col=row(lm); bf16 store + stats from exact fp32
  #pragma unroll
  for (int i = 0; i < 2; ++i){
    int e0 = (2*w+i)*16 + quad*4;
    f4 bv = *(const f4*)&bvec[e0];
    f4 sv = (f4)0.f, qv = (f4)0.f;
    #pragma unroll
    for (int rt = 0; rt < 4; ++rt){
      int row = rowbase + rt*16 + lm;
      f4 o = acc[i][rt] + bv;
      uint2 p; p.x = pk(o.x, o.y); p.y = pk(o.z, o.w);
      *(uint2*)&outpre[row*128 + e0] = p;
      sv += o; qv += o*o;
    }
    #pragma unroll
    for (int m = 1; m < 16; m <<= 1){
      sv.x+=__shfl_xor(sv.x,m); sv.y+=__shfl_xor(sv.y,m); sv.z+=__shfl_xor(sv.z,m); sv.w+=__shfl_xor(sv.w,m);
      qv.x+=__shfl_xor(qv.x,m); qv.y+=__shfl_xor(qv.y,m); qv.z+=__shfl_xor(qv.z,m); qv.w+=__shfl_xor(qv.w,m);
    }
    if (lm == 0){
      *(f4*)&g_part[bid][e0]       = sv;
      *(f4*)&g_part[bid][128 + e0] = qv;
    }
  }
}

// ---------------- final BN + leaky: read bf16 out_pre, write fp32 out ----------------
__global__ void k_bnout(const u16* __restrict__ outpre, float* __restrict__ outp){
  int idx = blockIdx.x*256 + threadIdx.x;
  int flat = idx*8;
  int o = flat & 127;
  uint4 v = *(const uint4*)(outpre + flat);
  u32 vv[4] = {v.x, v.y, v.z, v.w};
  float4 r0, r1;
  float rr[8];
  #pragma unroll
  for (int e = 0; e < 4; ++e){
    rr[2*e]   = lrelu(fmaf(b2f((u16)(vv[e] & 0xffff)), g_sb[2][0][o+2*e],   g_sb[2][1][o+2*e]));
    rr[2*e+1] = lrelu(fmaf(b2f((u16)(vv[e] >> 16)),    g_sb[2][0][o+2*e+1], g_sb[2][1][o+2*e+1]));
  }
  r0.x = rr[0]; r0.y = rr[1]; r0.z = rr[2]; r0.w = rr[3];
  r1.x = rr[4]; r1.y = rr[5]; r1.z = rr[6]; r1.w = rr[7];
  *(float4*)(outp + flat)     = r0;
  *(float4*)(outp + flat + 4) = r1;
}

extern "C" void kernel_launch(void* const* d_in, const int* in_sizes, int n_in,
                              void* d_out, int out_size, void* d_ws, size_t ws_size,
                              hipStream_t stream) {
  const float* x    = (const float*)d_in[0];
  const float* w1   = (const float*)d_in[1];
  const float* bn1g = (const float*)d_in[2];
  const float* bn1b = (const float*)d_in[3];
  const float* w2   = (const float*)d_in[4];
  const float* bn2g = (const float*)d_in[5];
  const float* bn2b = (const float*)d_in[6];
  const float* mapw = (const float*)d_in[7];
  const float* mapb = (const float*)d_in[8];
  const float* thw  = (const float*)d_in[9];
  const float* thb  = (const float*)d_in[10];
  const float* bnSg = (const float*)d_in[11];
  const float* bnSb = (const float*)d_in[12];
  float* outp = (float*)d_out;

  // ws (64 MB): spa (16M bf16; pre-BN2 until gemm0 activates in place; REUSED as bf16 out_pre
  // after adjagg) + agg (16M bf16)
  u16* spa    = (u16*)d_ws;
  u16* agg    = spa + 16777216;
  u16* outpre = spa;                       // spa dead after adjagg

  // d_out scratch phases: y1 bf16 (33 MB) -> mapped hi/lo planes (mh 32MB + ml 32MB) -> out fp32
  u16* y1b = (u16*)d_out;
  u16* mh  = (u16*)d_out;

  k_prepw<<<416, 256, 0, stream>>>(w1, w2, mapw, thw);
  k_conv1<<<2048, 256, 0, stream>>>(x, y1b);
  k_reduce<<<16, 256, 0, stream>>>(bn1g, bn1b, 0);
  k_conv2<<<2048, 256, 0, stream>>>(y1b, spa);
  k_reduce<<<16, 256, 0, stream>>>(bn2g, bn2b, 1);
  k_gemm0<<<2048, 256, 0, stream>>>(spa, spa, mapb, mh);
  k_adjagg<<<2048, 256, 0, stream>>>(mh, mh + 16777216, spa, agg);
  k_gemm1<<<2048, 256, 0, stream>>>(agg, thb, outpre);
  k_reduce<<<16, 256, 0, stream>>>(bnSg, bnSb, 2);
  k_bnout<<<8192, 256, 0, stream>>>(outpre, outp);
}

// Round 10
// 380.369 us; speedup vs baseline: 1.8201x; 1.0349x over previous
//
#include <hip/hip_runtime.h>

#define SLOPE 0.01f
#define EPSB 1e-5f
#define INV_CNT (1.0f/131072.0f)

typedef unsigned short u16;
typedef unsigned int u32;
typedef __attribute__((ext_vector_type(8))) short s16x8;
typedef __attribute__((ext_vector_type(4))) float f4;

__device__ float g_stats[3][2][128];   // [which][sum|sq][channel]
__device__ float g_sb[3][2][128];      // [which][scale|bias][channel]
__device__ float g_part[2048][256];    // per-block partial stats [block][sum128|sq128]
__device__ int   g_cnt[3];             // completion counters
__device__ u16 g_w1h[3][128][64];      // [k][co][ci] hi
__device__ u16 g_w1l[3][128][64];      // lo
__device__ u16 g_w2h[3][128][128];
__device__ u16 g_w2l[3][128][128];
__device__ u16 g_wmh[128][128];        // [e][d]
__device__ u16 g_wml[128][128];
__device__ u16 g_wqh[128][128];        // theta
__device__ u16 g_wql[128][128];

__device__ __forceinline__ float lrelu(float x){ return x > 0.f ? x : SLOPE*x; }
__device__ __forceinline__ u16 f2b(float f){
  u32 u = __float_as_uint(f);
  return (u16)((u + 0x7fffu + ((u >> 16) & 1u)) >> 16);   // RNE
}
__device__ __forceinline__ float b2f(u16 h){ return __uint_as_float(((u32)h) << 16); }
__device__ __forceinline__ u32 pk(float a, float b){ return (u32)f2b(a) | ((u32)f2b(b) << 16); }

// ---------------- prep: zero stats/counters + fp32 weights -> bf16 hi/lo ----------------
__global__ void k_prepw(const float* __restrict__ w1, const float* __restrict__ w2,
                        const float* __restrict__ mapw, const float* __restrict__ thw){
  int idx = blockIdx.x*256 + threadIdx.x;
  if (idx < 768) ((float*)g_stats)[idx] = 0.f;
  if (idx < 3) g_cnt[idx] = 0;
  if (idx < 24576){
    int kk = idx >> 13, r = idx & 8191, co = r >> 6, ci = r & 63;
    float v = w1[co*192 + ci*3 + kk];
    u16 h = f2b(v);
    g_w1h[kk][co][ci] = h; g_w1l[kk][co][ci] = f2b(v - b2f(h));
  } else if (idx < 73728){
    int j = idx - 24576;
    int kk = j >> 14, r = j & 16383, co = r >> 7, ci = r & 127;
    float v = w2[co*384 + ci*3 + kk];
    u16 h = f2b(v);
    g_w2h[kk][co][ci] = h; g_w2l[kk][co][ci] = f2b(v - b2f(h));
  } else if (idx < 90112){
    int j = idx - 73728;
    float v = mapw[j];
    u16 h = f2b(v);
    ((u16*)g_wmh)[j] = h; ((u16*)g_wml)[j] = f2b(v - b2f(h));
  } else if (idx < 106496){
    int j = idx - 90112;
    float v = thw[j];
    u16 h = f2b(v);
    ((u16*)g_wqh)[j] = h; ((u16*)g_wql)[j] = f2b(v - b2f(h));
  }
}

// ---------------- reduce partials -> g_stats; last block finalizes scale/bias ----------------
__global__ void k_reduce(const float* __restrict__ g, const float* __restrict__ bta, int which){
  const float* base = &g_part[blockIdx.x*128][0];
  int j = threadIdx.x;
  float s = 0.f;
  #pragma unroll 4
  for (int r = 0; r < 128; ++r) s += base[r*256 + j];
  atomicAdd(&((float*)g_stats)[which*256 + j], s);
  __threadfence();
  __shared__ int lastf;
  __syncthreads();
  if (threadIdx.x == 0) lastf = (atomicAdd(&g_cnt[which], 1) == 15) ? 1 : 0;
  __syncthreads();
  if (lastf){
    __threadfence();
    if (j < 128){
      float sm = atomicAdd(&g_stats[which][0][j], 0.f);   // coherent read
      float sq = atomicAdd(&g_stats[which][1][j], 0.f);
      float mean = sm * INV_CNT;
      float var  = sq * INV_CNT - mean*mean;
      float sc = g[j] * rsqrtf(var + EPSB);
      g_sb[which][0][j] = sc;
      g_sb[which][1][j] = bta[j] - mean*sc;
    }
  }
}

// ---------------- conv1 MFMA: weights direct-from-L2, 1 barrier; y1 stored bf16 (pre-BN1) ----------------
__global__ __launch_bounds__(256, 4) void k_conv1(const float* __restrict__ x, u16* __restrict__ y1b){
  __shared__ __align__(16) u16 a0h[2][34][72];
  __shared__ __align__(16) u16 a0l[2][34][72];
  const int bid = blockIdx.x;
  const int bn0 = bid*2;
  const int b = bn0 >> 8, n = bn0 & 255;
  const int tid = threadIdx.x;
  const int w = tid >> 6, l = tid & 63, quad = l >> 4, lm = l & 15;
  f4 acc[2][4];
  #pragma unroll
  for (int i = 0; i < 2; ++i)
    #pragma unroll
    for (int j = 0; j < 4; ++j) acc[i][j] = (f4)0.f;

  { // stage x -> a0h/a0l (hi/lo bf16), transposed to [t][ci]
    int nn = tid >> 7, rem = tid & 127, t = rem >> 2, ci0 = (rem & 3)*16;
    const float* px = x + ((b*32 + t)*256 + n + nn)*64 + ci0;
    u16 hh[16], ll[16];
    #pragma unroll
    for (int j = 0; j < 4; ++j){
      float4 v = *(const float4*)(px + 4*j);
      float vv[4] = {v.x, v.y, v.z, v.w};
      #pragma unroll
      for (int e = 0; e < 4; ++e){
        u16 h = f2b(vv[e]);
        hh[4*j+e] = h; ll[4*j+e] = f2b(vv[e] - b2f(h));
      }
    }
    *(uint4*)&a0h[nn][t+1][ci0]   = *(uint4*)&hh[0];
    *(uint4*)&a0h[nn][t+1][ci0+8] = *(uint4*)&hh[8];
    *(uint4*)&a0l[nn][t+1][ci0]   = *(uint4*)&ll[0];
    *(uint4*)&a0l[nn][t+1][ci0+8] = *(uint4*)&ll[8];
  }
  for (int u = tid; u < 288; u += 256){
    int a = u / 144, rr = u % 144, r = rr / 36, cw = rr % 36;
    u32* base = a ? (u32*)&a0l[r>>1][(r&1)*33][0] : (u32*)&a0h[r>>1][(r&1)*33][0];
    base[cw] = 0u;
  }
  __syncthreads();

  for (int kk = 0; kk < 3; ++kk){
    #pragma unroll
    for (int s = 0; s < 2; ++s){
      int ci0 = s*32 + quad*8;
      s16x8 wh[2], wl[2], bh[4], bl[4];
      #pragma unroll
      for (int i = 0; i < 2; ++i){
        wh[i] = *(const s16x8*)&g_w1h[kk][(2*w+i)*16 + lm][ci0];
        wl[i] = *(const s16x8*)&g_w1l[kk][(2*w+i)*16 + lm][ci0];
      }
      #pragma unroll
      for (int nt = 0; nt < 4; ++nt){
        bh[nt] = *(s16x8*)&a0h[nt>>1][(nt&1)*16 + lm + kk][ci0];
        bl[nt] = *(s16x8*)&a0l[nt>>1][(nt&1)*16 + lm + kk][ci0];
      }
      #pragma unroll
      for (int i = 0; i < 2; ++i)
        #pragma unroll
        for (int nt = 0; nt < 4; ++nt){
          acc[i][nt] = __builtin_amdgcn_mfma_f32_16x16x32_bf16(wh[i], bh[nt], acc[i][nt], 0, 0, 0);
          acc[i][nt] = __builtin_amdgcn_mfma_f32_16x16x32_bf16(wh[i], bl[nt], acc[i][nt], 0, 0, 0);
          acc[i][nt] = __builtin_amdgcn_mfma_f32_16x16x32_bf16(wl[i], bh[nt], acc[i][nt], 0, 0, 0);
        }
    }
  }
  // epilogue: D row=co(quad*4+reg), col=t(lm). Store bf16 (pre-BN1); stats from exact fp32.
  #pragma unroll
  for (int i = 0; i < 2; ++i){
    int co0 = (2*w+i)*16 + quad*4;
    float s0=0,s1=0,s2=0,s3=0,q0=0,q1=0,q2=0,q3=0;
    #pragma unroll
    for (int nt = 0; nt < 4; ++nt){
      f4 a = acc[i][nt];
      int nn = nt >> 1, t = (nt & 1)*16 + lm;
      uint2 p; p.x = pk(a.x, a.y); p.y = pk(a.z, a.w);
      *(uint2*)&y1b[((bn0+nn)*32 + t)*128 + co0] = p;
      s0+=a.x; s1+=a.y; s2+=a.z; s3+=a.w;
      q0+=a.x*a.x; q1+=a.y*a.y; q2+=a.z*a.z; q3+=a.w*a.w;
    }
    #pragma unroll
    for (int m = 1; m < 16; m <<= 1){
      s0+=__shfl_xor(s0,m); s1+=__shfl_xor(s1,m); s2+=__shfl_xor(s2,m); s3+=__shfl_xor(s3,m);
      q0+=__shfl_xor(q0,m); q1+=__shfl_xor(q1,m); q2+=__shfl_xor(q2,m); q3+=__shfl_xor(q3,m);
    }
    if (lm == 0){
      f4 sv = {s0,s1,s2,s3}, qv = {q0,q1,q2,q3};
      *(f4*)&g_part[bid][co0]       = sv;
      *(f4*)&g_part[bid][128 + co0] = qv;
    }
  }
}

// ---------------- conv2 MFMA: weights direct-from-L2, 1 barrier; y1 read bf16 ----------------
__global__ __launch_bounds__(256, 4) void k_conv2(const u16* __restrict__ y1b, u16* __restrict__ spa){
  __shared__ __align__(16) u16 a1s[2][34][136];
  const int bid = blockIdx.x;
  const int bn0 = bid*2;
  const int b = bn0 >> 8, n = bn0 & 255;
  const int tid = threadIdx.x;
  const int w = tid >> 6, l = tid & 63, quad = l >> 4, lm = l & 15;
  f4 acc2[4][2];
  #pragma unroll
  for (int mt = 0; mt < 4; ++mt)
    #pragma unroll
    for (int i = 0; i < 2; ++i) acc2[mt][i] = (f4)0.f;

  { // stage bn1+relu(y1 bf16) -> a1s
    int nn = tid >> 7, rem = tid & 127, t = rem >> 2, ci0 = (rem & 3)*32;
    const u16* py = y1b + ((bn0+nn)*32 + t)*128;
    #pragma unroll
    for (int j = 0; j < 4; ++j){
      uint4 v = *(const uint4*)(py + ci0 + 8*j);
      u32 vv[4] = {v.x, v.y, v.z, v.w};
      u16 oo[8];
      #pragma unroll
      for (int e = 0; e < 4; ++e){
        int ci = ci0 + 8*j + 2*e;
        oo[2*e]   = f2b(fmaxf(fmaf(b2f((u16)(vv[e] & 0xffff)), g_sb[0][0][ci],   g_sb[0][1][ci]),   0.f));
        oo[2*e+1] = f2b(fmaxf(fmaf(b2f((u16)(vv[e] >> 16)),    g_sb[0][0][ci+1], g_sb[0][1][ci+1]), 0.f));
      }
      *(uint4*)&a1s[nn][t+1][ci0 + 8*j] = *(uint4*)&oo[0];
    }
  }
  for (int u = tid; u < 272; u += 256){
    int r = u/68, cw = u%68;
    ((u32*)&a1s[r>>1][(r&1)*33][0])[cw] = 0u;
  }
  __syncthreads();

  for (int kk = 0; kk < 3; ++kk){
    #pragma unroll
    for (int s = 0; s < 4; ++s){
      int ci0 = s*32 + quad*8;
      s16x8 ax[4], bwh[2], bwl[2];
      #pragma unroll
      for (int i = 0; i < 2; ++i){
        bwh[i] = *(const s16x8*)&g_w2h[kk][(2*w+i)*16 + lm][ci0];
        bwl[i] = *(const s16x8*)&g_w2l[kk][(2*w+i)*16 + lm][ci0];
      }
      #pragma unroll
      for (int mt = 0; mt < 4; ++mt) ax[mt] = *(s16x8*)&a1s[mt>>1][(mt&1)*16 + lm + kk][ci0];
      #pragma unroll
      for (int mt = 0; mt < 4; ++mt)
        #pragma unroll
        for (int i = 0; i < 2; ++i){
          acc2[mt][i] = __builtin_amdgcn_mfma_f32_16x16x32_bf16(ax[mt], bwh[i], acc2[mt][i], 0, 0, 0);
          acc2[mt][i] = __builtin_amdgcn_mfma_f32_16x16x32_bf16(ax[mt], bwl[i], acc2[mt][i], 0, 0, 0);
        }
    }
  }
  // epilogue: D row=t(quad*4+reg), col=co(lm); permuted spa store (pre-BN2), partial stats
  #pragma unroll
  for (int i = 0; i < 2; ++i){
    int co = (2*w+i)*16 + lm;
    float s = 0.f, q = 0.f;
    #pragma unroll
    for (int mt = 0; mt < 4; ++mt){
      f4 a = acc2[mt][i];
      int off0 = co*32 + (mt&1)*16 + quad*4;       // off = co*32 + t
      int tp = off0 >> 7, cp = off0 & 127;
      int row = (b*32 + tp)*256 + (n + (mt>>1));
      uint2 p; p.x = pk(a.x, a.y); p.y = pk(a.z, a.w);
      *(uint2*)&spa[row*128 + cp] = p;
      s += a.x + a.y + a.z + a.w;
      q += a.x*a.x + a.y*a.y + a.z*a.z + a.w*a.w;
    }
    s += __shfl_xor(s, 16); s += __shfl_xor(s, 32);
    q += __shfl_xor(q, 16); q += __shfl_xor(q, 32);
    if (l < 16){
      g_part[bid][co]       = s;
      g_part[bid][128 + co] = q;
    }
  }
}

// ---------------- gemm0 (map) MFMA: BN2+relu inline; write-back activated spa; mapped hi/lo planes ----------------
__global__ __launch_bounds__(256, 4) void k_gemm0(const u16* A,
                                                  u16* spaw,
                                                  const float* __restrict__ bvec,
                                                  u16* __restrict__ mh){
  __shared__ __align__(16) u16 As[64][136];
  const u16* Wh = &g_wmh[0][0];
  const u16* Wl = &g_wml[0][0];
  const int bid = blockIdx.x;
  const int rowbase = bid * 64;
  const int tid = threadIdx.x;
  const int w = tid >> 6, l = tid & 63, quad = l >> 4, lm = l & 15;
  f4 acc[2][4];
  #pragma unroll
  for (int i = 0; i < 2; ++i)
    #pragma unroll
    for (int rt = 0; rt < 4; ++rt) acc[i][rt] = (f4)0.f;

  { int r = tid >> 2, c0 = (tid & 3)*32;
    int row = rowbase + r;
    // fused BN2+relu: channel = tp*4 + chunk, tp = (row>>8)&31, chunk = tid&3
    int c = ((row >> 8) & 31)*4 + (tid & 3);
    float sc = g_sb[1][0][c], bi = g_sb[1][1][c];
    #pragma unroll
    for (int j = 0; j < 4; ++j){
      uint4 v = *(const uint4*)&A[row*128 + c0 + 8*j];
      u32 vv[4] = {v.x, v.y, v.z, v.w};
      u16 oo[8];
      #pragma unroll
      for (int e = 0; e < 4; ++e){
        oo[2*e]   = f2b(fmaxf(fmaf(b2f((u16)(vv[e] & 0xffff)), sc, bi), 0.f));
        oo[2*e+1] = f2b(fmaxf(fmaf(b2f((u16)(vv[e] >> 16)),    sc, bi), 0.f));
      }
      uint4 ov = *(uint4*)&oo[0];
      *(uint4*)&As[r][c0 + 8*j] = ov;
      *(uint4*)&spaw[row*128 + c0 + 8*j] = ov;   // activated write-back
    }
  }
  __syncthreads();

  #pragma unroll
  for (int s = 0; s < 4; ++s){
    int k0 = s*32 + quad*8;
    s16x8 awh[2], awl[2], ba[4];
    #pragma unroll
    for (int i = 0; i < 2; ++i){
      awh[i] = *(const s16x8*)&Wh[((2*w+i)*16 + lm)*128 + k0];
      awl[i] = *(const s16x8*)&Wl[((2*w+i)*16 + lm)*128 + k0];
    }
    #pragma unroll
    for (int rt = 0; rt < 4; ++rt) ba[rt] = *(s16x8*)&As[rt*16 + lm][k0];
    #pragma unroll
    for (int i = 0; i < 2; ++i)
      #pragma unroll
      for (int rt = 0; rt < 4; ++rt){
        acc[i][rt] = __builtin_amdgcn_mfma_f32_16x16x32_bf16(awh[i], ba[rt], acc[i][rt], 0, 0, 0);
        acc[i][rt] = __builtin_amdgcn_mfma_f32_16x16x32_bf16(awl[i], ba[rt], acc[i][rt], 0, 0, 0);
      }
  }
  // epilogue: hi/lo planes, chunked [bp][dc][m][32]
  #pragma unroll
  for (int i = 0; i < 2; ++i){
    int e0 = (2*w+i)*16 + quad*4;
    f4 bv = *(const f4*)&bvec[e0];
    u16* ml = mh + 16777216;
    int dc = e0 >> 5, ec = e0 & 31;
    #pragma unroll
    for (int rt = 0; rt < 4; ++rt){
      int row = rowbase + rt*16 + lm;
      int bp = row >> 8, m = row & 255;
      f4 o = acc[i][rt] + bv;
      float fv[4] = {o.x, o.y, o.z, o.w};
      u16 hh[4], ll[4];
      #pragma unroll
      for (int e = 0; e < 4; ++e){
        u16 h = f2b(fv[e]);
        hh[e] = h; ll[e] = f2b(fv[e] - b2f(h));
      }
      int off = ((bp*4 + dc)*256 + m)*32 + ec;
      *(uint2*)&mh[off] = *(uint2*)&hh[0];
      *(uint2*)&ml[off] = *(uint2*)&ll[0];
    }
  }
}

// ---------------- fused adj+agg+theta MFMA; writes out_pre (bf16) + final-BN partials ----------------
__global__ __launch_bounds__(256) void k_adjagg(const u16* __restrict__ mh,
                                                const u16* __restrict__ ml,
                                                const u16* __restrict__ spa,
                                                const float* __restrict__ bvec,
                                                u16* __restrict__ outpre){
  __shared__ __align__(16) char smem[52224];
  u16 (*mbh)[40]   = (u16(*)[40])(smem);
  u16 (*mbl)[40]   = (u16(*)[40])(smem + 20480);
  u16 (*Ps)[264]   = (u16(*)[264])(smem);            // [64][264] = 33792 B
  u16 (*spasT)[72] = (u16(*)[72])(smem + 33792);     // [128][72] = 18432 B
  u16 (*aggs)[136] = (u16(*)[136])(smem + 33792);    // [64][136] = 17408 B (overlays spasT)
  // XCD-aware remap: 4 nt-blocks of one bp land consecutively on the same XCD
  const int rb = blockIdx.x;
  const int vb = (rb & 7)*256 + (rb >> 3);
  const int bp = vb >> 2;
  const int nt = vb & 3;
  const int tid = threadIdx.x;
  const int w = tid >> 6, l = tid & 63, quad = l >> 4, lm = l & 15;

  // ---- phase 1: S rows (wave w -> row-tile w) x all 256 cols, hi/lo 3-term ----
  f4 sacc[16];
  #pragma unroll
  for (int ct = 0; ct < 16; ++ct) sacc[ct] = (f4)0.f;

  for (int dc = 0; dc < 4; ++dc){
    __syncthreads();
    { // pure copy staging from pre-split chunked planes (coalesced, conflict-free)
      const u16* srch = mh + ((bp*4 + dc) << 13);
      const u16* srcl = ml + ((bp*4 + dc) << 13);
      int m0 = tid >> 2, seg = (tid & 3)*8;
      #pragma unroll
      for (int r = 0; r < 4; ++r){
        int m = m0 + r*64;
        *(uint4*)&mbh[m][seg] = *(const uint4*)&srch[m*32 + seg];
        *(uint4*)&mbl[m][seg] = *(const uint4*)&srcl[m*32 + seg];
      }
    }
    __syncthreads();
    s16x8 amh = *(s16x8*)&mbh[nt*64 + w*16 + lm][quad*8];
    s16x8 aml = *(s16x8*)&mbl[nt*64 + w*16 + lm][quad*8];
    #pragma unroll
    for (int ct = 0; ct < 16; ++ct){
      s16x8 bmh = *(s16x8*)&mbh[ct*16 + lm][quad*8];
      s16x8 bml = *(s16x8*)&mbl[ct*16 + lm][quad*8];
      sacc[ct] = __builtin_amdgcn_mfma_f32_16x16x32_bf16(amh, bmh, sacc[ct], 0, 0, 0);
      sacc[ct] = __builtin_amdgcn_mfma_f32_16x16x32_bf16(amh, bml, sacc[ct], 0, 0, 0);
      sacc[ct] = __builtin_amdgcn_mfma_f32_16x16x32_bf16(aml, bmh, sacc[ct], 0, 0, 0);
    }
  }
  __syncthreads();   // all mbuf reads done; Ps may now overlay

  // ---- softmax (regs only) -> Ps[row][m] bf16 ----
  #pragma unroll
  for (int r = 0; r < 4; ++r){
    int rowg = nt*64 + w*16 + quad*4 + r;
    float v[16]; float mx = -3.0e38f;
    #pragma unroll
    for (int ct = 0; ct < 16; ++ct){
      float t = sacc[ct][r];
      if (ct*16 + lm == rowg) t -= 1e8f;
      t = lrelu(t);
      v[ct] = t; mx = fmaxf(mx, t);
    }
    #pragma unroll
    for (int m = 1; m < 16; m <<= 1) mx = fmaxf(mx, __shfl_xor(mx, m));
    float sum = 0.f;
    #pragma unroll
    for (int ct = 0; ct < 16; ++ct){ float e = __expf(v[ct] - mx); v[ct] = e; sum += e; }
    #pragma unroll
    for (int m = 1; m < 16; m <<= 1) sum += __shfl_xor(sum, m);
    float inv = 1.0f / sum;
    #pragma unroll
    for (int ct = 0; ct < 16; ++ct)
      Ps[w*16 + quad*4 + r][ct*16 + lm] = f2b(v[ct] * inv);
  }

  // ---- phase 2: agg = P @ spa (+ spa for +I). spa pre-activated; pure copy transpose. ----
  f4 acc2[2][4];
  #pragma unroll
  for (int i = 0; i < 2; ++i)
    #pragma unroll
    for (int rt = 0; rt < 4; ++rt) acc2[i][rt] = (f4)0.f;

  for (int mc2 = 0; mc2 < 4; ++mc2){
    __syncthreads();
    { // transpose-stage spa[64 m][128 d] -> spasT[128][72]
      int mlo = tid & 63;
      int db = (tid >> 6)*8;
      const u16* ps = spa + (bp*256 + mc2*64 + mlo)*128;
      #pragma unroll
      for (int r = 0; r < 4; ++r){
        int d0 = db + r*32;
        uint4 v = *(const uint4*)(ps + d0);
        u16 h[8]; *(uint4*)&h[0] = v;
        #pragma unroll
        for (int j = 0; j < 8; ++j) spasT[d0+j][mlo] = h[j];
      }
    }
    __syncthreads();
    #pragma unroll
    for (int ks = 0; ks < 2; ++ks){
      int m0 = ks*32 + quad*8;
      s16x8 afs[2], bfp[4];
      #pragma unroll
      for (int i = 0; i < 2; ++i) afs[i] = *(s16x8*)&spasT[(2*w+i)*16 + lm][m0];
      #pragma unroll
      for (int rt = 0; rt < 4; ++rt) bfp[rt] = *(s16x8*)&Ps[rt*16 + lm][mc2*64 + m0];
      #pragma unroll
      for (int i = 0; i < 2; ++i)
        #pragma unroll
        for (int rt = 0; rt < 4; ++rt)
          acc2[i][rt] = __builtin_amdgcn_mfma_f32_16x16x32_bf16(afs[i], bfp[rt], acc2[i][rt], 0, 0, 0);
    }
  }

  // ---- +I, stash agg tile (bf16) into LDS (overlay spasT region) ----
  __syncthreads();   // all spasT/Ps reads done
  #pragma unroll
  for (int i = 0; i < 2; ++i){
    int d0 = (2*w+i)*16 + quad*4;
    #pragma unroll
    for (int rt = 0; rt < 4; ++rt){
      int grow = bp*256 + nt*64 + rt*16 + lm;
      uint2 sp = *(const uint2*)&spa[grow*128 + d0];
      f4 a = acc2[i][rt];
      a.x += b2f((u16)(sp.x & 0xffff)); a.y += b2f((u16)(sp.x >> 16));
      a.z += b2f((u16)(sp.y & 0xffff)); a.w += b2f((u16)(sp.y >> 16));
      uint2 p; p.x = pk(a.x, a.y); p.y = pk(a.z, a.w);
      *(uint2*)&aggs[rt*16 + lm][d0] = p;
    }
  }
  __syncthreads();

  // ---- phase 3 (fused gemm1): out[64r][128e] = aggs @ thetaW^T (hi/lo), theta from L2 ----
  const u16* Wh = &g_wqh[0][0];
  const u16* Wl = &g_wql[0][0];
  f4 oacc[2][4];
  #pragma unroll
  for (int i = 0; i < 2; ++i)
    #pragma unroll
    for (int rt = 0; rt < 4; ++rt) oacc[i][rt] = (f4)0.f;

  #pragma unroll
  for (int s = 0; s < 4; ++s){
    int k0 = s*32 + quad*8;
    s16x8 awh[2], awl[2], ba[4];
    #pragma unroll
    for (int i = 0; i < 2; ++i){
      awh[i] = *(const s16x8*)&Wh[((2*w+i)*16 + lm)*128 + k0];
      awl[i] = *(const s16x8*)&Wl[((2*w+i)*16 + lm)*128 + k0];
    }
    #pragma unroll
    for (int rt = 0; rt < 4; ++rt) ba[rt] = *(s16x8*)&aggs[rt*16 + lm][k0];
    #pragma unroll
    for (int i = 0; i < 2; ++i)
      #pragma unroll
      for (int rt = 0; rt < 4; ++rt){
        oacc[i][rt] = __builtin_amdgcn_mfma_f32_16x16x32_bf16(awh[i], ba[rt], oacc[i][rt], 0, 0, 0);
        oacc[i][rt] = __builtin_amdgcn_mfma_f32_16x16x32_bf16(awl[i], ba[rt], oacc[i][rt], 0, 0, 0);
      }
  }
  // epilogue: D row=e(quad*4+reg), col=local row(lm); bf16 out_pre + stats from exact fp32
  #pragma unroll
  for (int i = 0; i < 2; ++i){
    int e0 = (2*w+i)*16 + quad*4;
    f4 bv = *(const f4*)&bvec[e0];
    f4 sv = (f4)0.f, qv = (f4)0.f;
    #pragma unroll
    for (int rt = 0; rt < 4; ++rt){
      int grow = bp*256 + nt*64 + rt*16 + lm;
      f4 o = oacc[i][rt] + bv;
      uint2 p; p.x = pk(o.x, o.y); p.y = pk(o.z, o.w);
      *(uint2*)&outpre[grow*128 + e0] = p;
      sv += o; qv += o*o;
    }
    #pragma unroll
    for (int m = 1; m < 16; m <<= 1){
      sv.x+=__shfl_xor(sv.x,m); sv.y+=__shfl_xor(sv.y,m); sv.z+=__shfl_xor(sv.z,m); sv.w+=__shfl_xor(sv.w,m);
      qv.x+=__shfl_xor(qv.x,m); qv.y+=__shfl_xor(qv.y,m); qv.z+=__shfl_xor(qv.z,m); qv.w+=__shfl_xor(qv.w,m);
    }
    if (lm == 0){
      *(f4*)&g_part[rb][e0]       = sv;
      *(f4*)&g_part[rb][128 + e0] = qv;
    }
  }
}

// ---------------- final BN + leaky: read bf16 out_pre, write fp32 out ----------------
__global__ void k_bnout(const u16* __restrict__ outpre, float* __restrict__ outp){
  int idx = blockIdx.x*256 + threadIdx.x;
  int flat = idx*8;
  int o = flat & 127;
  uint4 v = *(const uint4*)(outpre + flat);
  u32 vv[4] = {v.x, v.y, v.z, v.w};
  float4 r0, r1;
  float rr[8];
  #pragma unroll
  for (int e = 0; e < 4; ++e){
    rr[2*e]   = lrelu(fmaf(b2f((u16)(vv[e] & 0xffff)), g_sb[2][0][o+2*e],   g_sb[2][1][o+2*e]));
    rr[2*e+1] = lrelu(fmaf(b2f((u16)(vv[e] >> 16)),    g_sb[2][0][o+2*e+1], g_sb[2][1][o+2*e+1]));
  }
  r0.x = rr[0]; r0.y = rr[1]; r0.z = rr[2]; r0.w = rr[3];
  r1.x = rr[4]; r1.y = rr[5]; r1.z = rr[6]; r1.w = rr[7];
  *(float4*)(outp + flat)     = r0;
  *(float4*)(outp + flat + 4) = r1;
}

extern "C" void kernel_launch(void* const* d_in, const int* in_sizes, int n_in,
                              void* d_out, int out_size, void* d_ws, size_t ws_size,
                              hipStream_t stream) {
  const float* x    = (const float*)d_in[0];
  const float* w1   = (const float*)d_in[1];
  const float* bn1g = (const float*)d_in[2];
  const float* bn1b = (const float*)d_in[3];
  const float* w2   = (const float*)d_in[4];
  const float* bn2g = (const float*)d_in[5];
  const float* bn2b = (const float*)d_in[6];
  const float* mapw = (const float*)d_in[7];
  const float* mapb = (const float*)d_in[8];
  const float* thw  = (const float*)d_in[9];
  const float* thb  = (const float*)d_in[10];
  const float* bnSg = (const float*)d_in[11];
  const float* bnSb = (const float*)d_in[12];
  float* outp = (float*)d_out;

  // ws (64 MB): spa (16M bf16; pre-BN2 until gemm0 activates in place) + outpre (16M bf16,
  // formerly agg — adjagg now writes out_pre directly; agg never materialized)
  u16* spa    = (u16*)d_ws;
  u16* outpre = spa + 16777216;

  // d_out scratch phases: y1 bf16 (33 MB) -> mapped hi/lo planes (mh 32MB + ml 32MB) -> out fp32
  u16* y1b = (u16*)d_out;
  u16* mh  = (u16*)d_out;

  k_prepw<<<416, 256, 0, stream>>>(w1, w2, mapw, thw);
  k_conv1<<<2048, 256, 0, stream>>>(x, y1b);
  k_reduce<<<16, 256, 0, stream>>>(bn1g, bn1b, 0);
  k_conv2<<<2048, 256, 0, stream>>>(y1b, spa);
  k_reduce<<<16, 256, 0, stream>>>(bn2g, bn2b, 1);
  k_gemm0<<<2048, 256, 0, stream>>>(spa, spa, mapb, mh);
  k_adjagg<<<2048, 256, 0, stream>>>(mh, mh + 16777216, spa, thb, outpre);
  k_reduce<<<16, 256, 0, stream>>>(bnSg, bnSb, 2);
  k_bnout<<<8192, 256, 0, stream>>>(outpre, outp);
}